// Round 1
// baseline (2998.435 us; speedup 1.0000x reference)
//
#include <hip/hip_runtime.h>
#include <cstddef>

// Problem constants
constexpr int kB   = 2;
constexpr int kS   = 2048;
constexpr int kHID = 2048;
constexpr int kH   = 16;
constexpr int kHKV = 4;
constexpr int kD   = 128;
constexpr int kL   = 64;
constexpr int kNRep = kH / kHKV;          // 4
constexpr int kTok = kB * kS;             // 4096 tokens

// ---------------------------------------------------------------------------
// Tiled fp32 GEMM: C[M,N] = A[M,K] @ B[K,N], all row-major.
// 64x64 tile, BK=16, 256 threads, 4x4 per thread.
// REMAP: B row r is fetched from Wo row (r>>6)*128 + (r&63)  (skip zero pad).
// ---------------------------------------------------------------------------
template <bool REMAP>
__global__ __launch_bounds__(256) void gemm64(const float* __restrict__ A,
                                              const float* __restrict__ Bm,
                                              float* __restrict__ C,
                                              int M, int N, int K) {
  constexpr int BM = 64, BN = 64, BK = 16;
  __shared__ float At[BK][BM + 4];   // transposed A tile; row = 68 floats -> 16B-aligned rows
  __shared__ float Bs[BK][BN];
  const int tid = threadIdx.x;
  const int tx = tid & 15, ty = tid >> 4;
  const int row0 = blockIdx.y * BM, col0 = blockIdx.x * BN;

  float acc[4][4] = {};

  for (int k0 = 0; k0 < K; k0 += BK) {
    // A tile: 64 rows x 16 k. Thread t loads A[row0 + t/4][k0 + (t%4)*4 ..+3]
    {
      const int ar = tid >> 2;
      const int ac = (tid & 3) << 2;
      const float4 av = *reinterpret_cast<const float4*>(
          &A[(size_t)(row0 + ar) * K + (k0 + ac)]);
      At[ac + 0][ar] = av.x;
      At[ac + 1][ar] = av.y;
      At[ac + 2][ar] = av.z;
      At[ac + 3][ar] = av.w;
      // B tile: 16 rows x 64 cols. Thread t loads B[k0 + t/16][col0 + (t%16)*4]
      const int br = tid >> 4;
      const int bc = (tid & 15) << 2;
      int brow = k0 + br;
      if (REMAP) brow = ((brow >> 6) << 7) + (brow & 63);
      const float4 bv = *reinterpret_cast<const float4*>(
          &Bm[(size_t)brow * N + (col0 + bc)]);
      *reinterpret_cast<float4*>(&Bs[br][bc]) = bv;
    }
    __syncthreads();
#pragma unroll
    for (int kk = 0; kk < BK; ++kk) {
      const float4 a4 = *reinterpret_cast<const float4*>(&At[kk][ty << 2]);
      const float4 b4 = *reinterpret_cast<const float4*>(&Bs[kk][tx << 2]);
      const float a[4] = {a4.x, a4.y, a4.z, a4.w};
      const float b[4] = {b4.x, b4.y, b4.z, b4.w};
#pragma unroll
      for (int i = 0; i < 4; ++i)
#pragma unroll
        for (int j = 0; j < 4; ++j) acc[i][j] += a[i] * b[j];
    }
    __syncthreads();
  }
#pragma unroll
  for (int i = 0; i < 4; ++i) {
    const float4 v = make_float4(acc[i][0], acc[i][1], acc[i][2], acc[i][3]);
    *reinterpret_cast<float4*>(
        &C[(size_t)(row0 + (ty << 2) + i) * N + col0 + (tx << 2)]) = v;
  }
}

// ---------------------------------------------------------------------------
// RoPE in-place on buf laid out [token][h][d] (d = 128, rotate-half pairing).
// One thread per (token, head, pair i in [0,64)).
// ---------------------------------------------------------------------------
__global__ void rope_kernel(float* __restrict__ buf,
                            const int* __restrict__ pos_ids,
                            int nh, int total) {
  const int idx = blockIdx.x * 256 + threadIdx.x;
  if (idx >= total) return;
  const int i = idx & 63;
  const int h = (idx >> 6) % nh;
  const int t = idx / (64 * nh);
  const float p = (float)pos_ids[t];
  // inv_freq = 10000^(-i/64) = exp(-i * ln(10000)/64)
  const float inv_freq = expf(-(float)i * (9.210340371976184f / 64.0f));
  const float ang = p * inv_freq;
  const float c = cosf(ang);
  const float sn = sinf(ang);
  float* bp = buf + ((size_t)t * nh + h) * kD;
  const float t1 = bp[i];
  const float t2 = bp[i + 64];
  bp[i]      = t1 * c - t2 * sn;
  bp[i + 64] = t2 * c + t1 * sn;
}

// ---------------------------------------------------------------------------
// Latent projection: out[b][h][s][l] = sum_d in[(b,s,h,d)] * W[d][l]
// in layout: [token][nh][128]; out layout: [(b*nh+h)][s][64].
// W (128x64) staged in LDS. Block: 256 threads, 64 tokens.
// ---------------------------------------------------------------------------
__global__ __launch_bounds__(256) void latent_proj(const float* __restrict__ in,
                                                   const float* __restrict__ W,
                                                   float* __restrict__ out,
                                                   int nh) {
  __shared__ float Ws[kD][kL];
  const int tid = threadIdx.x;
  for (int i = tid; i < kD * kL; i += 256) Ws[i >> 6][i & 63] = W[i];
  __syncthreads();
  const int bh = blockIdx.y;
  const int b = bh / nh, h = bh % nh;
  const int s0 = blockIdx.x * 64;
  const int l = tid & 63;
  const int sr = tid >> 6;
  for (int s = s0 + sr; s < s0 + 64; s += 4) {
    const float* ip = in + ((size_t)(b * kS + s) * nh + h) * kD;
    float acc = 0.f;
    for (int d0 = 0; d0 < kD; d0 += 4) {
      const float4 iv = *reinterpret_cast<const float4*>(ip + d0);
      acc += iv.x * Ws[d0][l] + iv.y * Ws[d0 + 1][l] +
             iv.z * Ws[d0 + 2][l] + iv.w * Ws[d0 + 3][l];
    }
    out[((size_t)(b * nh + h) * kS + s) * kL + l] = acc;
  }
}

// ---------------------------------------------------------------------------
// fp32 flash attention, causal. Block = 64 threads = 64 query rows (1 wave).
// grid = (S/64, B*H). L = 64. Masked-out scores -> exp underflows to 0,
// exactly matching the reference's -1e9 additive mask.
// Output written in [token][h*64 + l] layout (feeds the K=1024 output GEMM).
// ---------------------------------------------------------------------------
__global__ __launch_bounds__(64) void flash_attn(const float* __restrict__ ql,
                                                 const float* __restrict__ kl,
                                                 const float* __restrict__ vl,
                                                 float* __restrict__ attn_out) {
  __shared__ float Kt[64][64];
  __shared__ float Vt[64][64];
  __shared__ float St[64][65];
  const int tid = threadIdx.x;             // query row within tile
  const int q0 = blockIdx.x * 64;
  const int bh = blockIdx.y;               // b*16 + h
  const int b = bh >> 4, h = bh & 15;
  const int hk = h >> 2;                   // kv head = h / n_rep
  const float* qrow = ql + ((size_t)bh * kS + q0 + tid) * kL;

  float Q[64];
#pragma unroll
  for (int i = 0; i < 16; ++i) {
    const float4 v = *reinterpret_cast<const float4*>(qrow + i * 4);
    Q[i * 4] = v.x; Q[i * 4 + 1] = v.y; Q[i * 4 + 2] = v.z; Q[i * 4 + 3] = v.w;
  }
  float O[64];
#pragma unroll
  for (int i = 0; i < 64; ++i) O[i] = 0.f;
  float m = -3.0e38f, lsum = 0.f;

  const size_t kvbase = (size_t)(b * kHKV + hk) * kS * kL;

  for (int j0 = 0; j0 <= q0; j0 += 64) {
    __syncthreads();  // previous tile's Kt/Vt reads complete
    for (int i = tid; i < 64 * 16; i += 64) {
      const int r = i >> 4, c4 = (i & 15) << 2;
      *reinterpret_cast<float4*>(&Kt[r][c4]) =
          *reinterpret_cast<const float4*>(kl + kvbase + (size_t)(j0 + r) * kL + c4);
      *reinterpret_cast<float4*>(&Vt[r][c4]) =
          *reinterpret_cast<const float4*>(vl + kvbase + (size_t)(j0 + r) * kL + c4);
    }
    __syncthreads();
    const bool diag = (j0 == q0);
    float mt = -3.0e38f;
#pragma unroll 1
    for (int kk = 0; kk < 64; ++kk) {
      float s = 0.f;
#pragma unroll
      for (int l4 = 0; l4 < 64; ++l4) s += Q[l4] * Kt[kk][l4];
      s *= 0.125f;                          // 1/sqrt(L)
      if (diag && kk > tid) s = -3.0e38f;   // causal mask
      St[tid][kk] = s;
      mt = fmaxf(mt, s);
    }
    const float mnew = fmaxf(m, mt);
    const float corr = __expf(m - mnew);    // first tile: exp(-3e38) == 0
    lsum *= corr;
#pragma unroll
    for (int l = 0; l < 64; ++l) O[l] *= corr;
#pragma unroll 1
    for (int kk = 0; kk < 64; ++kk) {
      const float p = __expf(St[tid][kk] - mnew);
      lsum += p;
#pragma unroll
      for (int l = 0; l < 64; ++l) O[l] += p * Vt[kk][l];
    }
    m = mnew;
  }

  const float inv = 1.f / lsum;
  float* op = attn_out + (size_t)(b * kS + q0 + tid) * (kH * kL) + h * kL;
#pragma unroll
  for (int i = 0; i < 16; ++i) {
    float4 v;
    v.x = O[i * 4] * inv;     v.y = O[i * 4 + 1] * inv;
    v.z = O[i * 4 + 2] * inv; v.w = O[i * 4 + 3] * inv;
    *reinterpret_cast<float4*>(op + i * 4) = v;
  }
}

// ---------------------------------------------------------------------------
extern "C" void kernel_launch(void* const* d_in, const int* in_sizes, int n_in,
                              void* d_out, int out_size, void* d_ws, size_t ws_size,
                              hipStream_t stream) {
  const float* x    = (const float*)d_in[0];
  const int*   pos  = (const int*)d_in[1];
  // d_in[2] = attention_mask (causal, handled analytically)
  const float* Wq   = (const float*)d_in[3];
  const float* Wk   = (const float*)d_in[4];
  const float* Wv   = (const float*)d_in[5];
  const float* Wql  = (const float*)d_in[6];
  const float* Wkl  = (const float*)d_in[7];
  const float* Wvl  = (const float*)d_in[8];
  const float* Wo   = (const float*)d_in[9];
  float* out = (float*)d_out;

  // Workspace carve (floats). q_buf reuses d_out (same size: 4096*2048),
  // consumed by rope+latent_proj before the final GEMM overwrites d_out.
  float* q_buf = (float*)d_out;                       // 4096 * 2048
  float* ws    = (float*)d_ws;
  float* k_buf = ws;                                  // 4096 * 512
  float* v_buf = k_buf + (size_t)kTok * kHKV * kD;    // 4096 * 512
  float* q_l   = v_buf + (size_t)kTok * kHKV * kD;    // 2*16*2048*64
  float* k_l   = q_l   + (size_t)kB * kH * kS * kL;   // 2*4*2048*64
  float* v_l   = k_l   + (size_t)kB * kHKV * kS * kL;
  float* attn  = v_l   + (size_t)kB * kHKV * kS * kL; // 4096 * 1024

  // 1) Projections
  gemm64<false><<<dim3(kH * kD / 64, kTok / 64), 256, 0, stream>>>(
      x, Wq, q_buf, kTok, kH * kD, kHID);
  gemm64<false><<<dim3(kHKV * kD / 64, kTok / 64), 256, 0, stream>>>(
      x, Wk, k_buf, kTok, kHKV * kD, kHID);
  gemm64<false><<<dim3(kHKV * kD / 64, kTok / 64), 256, 0, stream>>>(
      x, Wv, v_buf, kTok, kHKV * kD, kHID);

  // 2) RoPE (in-place) on q and k
  {
    const int totq = kTok * kH * 64;
    rope_kernel<<<(totq + 255) / 256, 256, 0, stream>>>(q_buf, pos, kH, totq);
    const int totk = kTok * kHKV * 64;
    rope_kernel<<<(totk + 255) / 256, 256, 0, stream>>>(k_buf, pos, kHKV, totk);
  }

  // 3) Latent projections
  latent_proj<<<dim3(kS / 64, kB * kH), 256, 0, stream>>>(q_buf, Wql, q_l, kH);
  latent_proj<<<dim3(kS / 64, kB * kHKV), 256, 0, stream>>>(k_buf, Wkl, k_l, kHKV);
  latent_proj<<<dim3(kS / 64, kB * kHKV), 256, 0, stream>>>(v_buf, Wvl, v_l, kHKV);

  // 4) Flash attention -> attn in [token][h*64+l] layout
  flash_attn<<<dim3(kS / 64, kB * kH), 64, 0, stream>>>(q_l, k_l, v_l, attn);

  // 5) Output GEMM: (4096 x 1024) @ Wo[remapped rows] -> d_out (4096 x 2048)
  gemm64<true><<<dim3(kHID / 64, kTok / 64), 256, 0, stream>>>(
      attn, Wo, out, kTok, kHID, kH * kL);
}

// Round 2
// 1316.219 us; speedup vs baseline: 2.2781x; 2.2781x over previous
//
#include <hip/hip_runtime.h>
#include <cstddef>

// Problem constants
constexpr int kB   = 2;
constexpr int kS   = 2048;
constexpr int kHID = 2048;
constexpr int kH   = 16;
constexpr int kHKV = 4;
constexpr int kD   = 128;
constexpr int kL   = 64;
constexpr int kTok = kB * kS;             // 4096 tokens

typedef __attribute__((ext_vector_type(8))) short bf16x8;
typedef __attribute__((ext_vector_type(4))) float f32x4;

static __device__ inline short f2bf(float f) {
  union { float f; unsigned u; } v{f};
  const unsigned r = (v.u + 0x7fff + ((v.u >> 16) & 1)) >> 16;
  return (short)r;
}

static __device__ inline bf16x8 pack8(float4 a, float4 b) {
  bf16x8 r;
  r[0] = f2bf(a.x); r[1] = f2bf(a.y); r[2] = f2bf(a.z); r[3] = f2bf(a.w);
  r[4] = f2bf(b.x); r[5] = f2bf(b.y); r[6] = f2bf(b.z); r[7] = f2bf(b.w);
  return r;
}

// ---------------------------------------------------------------------------
// Tiled fp32 GEMM: C[M,N] = A[M,K] @ B[K,N], all row-major.
// 64x64 tile, BK=16, 256 threads, 4x4 per thread.
// REMAP: B row r is fetched from Wo row (r>>6)*128 + (r&63)  (skip zero pad).
// ---------------------------------------------------------------------------
template <bool REMAP>
__global__ __launch_bounds__(256) void gemm64(const float* __restrict__ A,
                                              const float* __restrict__ Bm,
                                              float* __restrict__ C,
                                              int M, int N, int K) {
  constexpr int BM = 64, BN = 64, BK = 16;
  __shared__ float At[BK][BM + 4];
  __shared__ float Bs[BK][BN];
  const int tid = threadIdx.x;
  const int tx = tid & 15, ty = tid >> 4;
  const int row0 = blockIdx.y * BM, col0 = blockIdx.x * BN;

  float acc[4][4] = {};

  for (int k0 = 0; k0 < K; k0 += BK) {
    {
      const int ar = tid >> 2;
      const int ac = (tid & 3) << 2;
      const float4 av = *reinterpret_cast<const float4*>(
          &A[(size_t)(row0 + ar) * K + (k0 + ac)]);
      At[ac + 0][ar] = av.x;
      At[ac + 1][ar] = av.y;
      At[ac + 2][ar] = av.z;
      At[ac + 3][ar] = av.w;
      const int br = tid >> 4;
      const int bc = (tid & 15) << 2;
      int brow = k0 + br;
      if (REMAP) brow = ((brow >> 6) << 7) + (brow & 63);
      const float4 bv = *reinterpret_cast<const float4*>(
          &Bm[(size_t)brow * N + (col0 + bc)]);
      *reinterpret_cast<float4*>(&Bs[br][bc]) = bv;
    }
    __syncthreads();
#pragma unroll
    for (int kk = 0; kk < BK; ++kk) {
      const float4 a4 = *reinterpret_cast<const float4*>(&At[kk][ty << 2]);
      const float4 b4 = *reinterpret_cast<const float4*>(&Bs[kk][tx << 2]);
      const float a[4] = {a4.x, a4.y, a4.z, a4.w};
      const float b[4] = {b4.x, b4.y, b4.z, b4.w};
#pragma unroll
      for (int i = 0; i < 4; ++i)
#pragma unroll
        for (int j = 0; j < 4; ++j) acc[i][j] += a[i] * b[j];
    }
    __syncthreads();
  }
#pragma unroll
  for (int i = 0; i < 4; ++i) {
    const float4 v = make_float4(acc[i][0], acc[i][1], acc[i][2], acc[i][3]);
    *reinterpret_cast<float4*>(
        &C[(size_t)(row0 + (ty << 2) + i) * N + col0 + (tx << 2)]) = v;
  }
}

// ---------------------------------------------------------------------------
// RoPE in-place on buf laid out [token][h][d] (d = 128, rotate-half pairing).
// ---------------------------------------------------------------------------
__global__ void rope_kernel(float* __restrict__ buf,
                            const int* __restrict__ pos_ids,
                            int nh, int total) {
  const int idx = blockIdx.x * 256 + threadIdx.x;
  if (idx >= total) return;
  const int i = idx & 63;
  const int h = (idx >> 6) % nh;
  const int t = idx / (64 * nh);
  const float p = (float)pos_ids[t];
  const float inv_freq = expf(-(float)i * (9.210340371976184f / 64.0f));
  const float ang = p * inv_freq;
  const float c = cosf(ang);
  const float sn = sinf(ang);
  float* bp = buf + ((size_t)t * nh + h) * kD;
  const float t1 = bp[i];
  const float t2 = bp[i + 64];
  bp[i]      = t1 * c - t2 * sn;
  bp[i + 64] = t2 * c + t1 * sn;
}

// ---------------------------------------------------------------------------
// Latent projection: out[(b*nh+h)][s][64] = in[(b,s,h,:128)] @ W[128][64]
// ---------------------------------------------------------------------------
__global__ __launch_bounds__(256) void latent_proj(const float* __restrict__ in,
                                                   const float* __restrict__ W,
                                                   float* __restrict__ out,
                                                   int nh) {
  __shared__ float Ws[kD][kL];
  const int tid = threadIdx.x;
  for (int i = tid; i < kD * kL; i += 256) Ws[i >> 6][i & 63] = W[i];
  __syncthreads();
  const int bh = blockIdx.y;
  const int b = bh / nh, h = bh % nh;
  const int s0 = blockIdx.x * 64;
  const int l = tid & 63;
  const int sr = tid >> 6;
  for (int s = s0 + sr; s < s0 + 64; s += 4) {
    const float* ip = in + ((size_t)(b * kS + s) * nh + h) * kD;
    float acc = 0.f;
    for (int d0 = 0; d0 < kD; d0 += 4) {
      const float4 iv = *reinterpret_cast<const float4*>(ip + d0);
      acc += iv.x * Ws[d0][l] + iv.y * Ws[d0 + 1][l] +
             iv.z * Ws[d0 + 2][l] + iv.w * Ws[d0 + 3][l];
    }
    out[((size_t)(b * nh + h) * kS + s) * kL + l] = acc;
  }
}

// ---------------------------------------------------------------------------
// MFMA flash attention, causal, bf16 compute / fp32 accumulate.
// Block = 256 threads (4 waves). Block handles 64 q rows of one (b,h);
// wave w owns q rows [w*16, w*16+16). grid = (S/64, B*H).
//
// Per 64-key tile: stage K[64][64] (row-major bf16) and V^T[64][64] in LDS
// (rows padded +8 bf16 -> 2-way bank aliasing only), compute
// S = Q@K^T with mfma_f32_16x16x32_bf16 (A = Q frag, B = K^T frag: both are
// 16B contiguous row reads), online softmax in D-layout
// (row=(lane>>4)*4+reg, col=lane&15; 16-lane shfl_xor max-reduce), write
// P (bf16) to wave-private LDS rows, then O += P@V via the same MFMA with
// B read from V^T. lsum is kept as a per-lane partial (its cross-lane
// reduction commutes with the per-row rescales) and reduced once at the end.
// ---------------------------------------------------------------------------
__global__ __launch_bounds__(256) void flash_attn_mfma(
    const float* __restrict__ ql, const float* __restrict__ kl,
    const float* __restrict__ vl, float* __restrict__ attn_out) {
  constexpr int LDK = 72;                      // 64 + 8 pad (bf16 elems)
  __shared__ short Kt[64 * LDK];
  __shared__ short Vt[64 * LDK];
  __shared__ short Pt[64 * LDK];

  const int tid = threadIdx.x;
  const int lane = tid & 63;
  const int w = tid >> 6;                      // wave 0..3
  const int lr = lane & 15;                    // A-row / B-col / D-col
  const int lk = lane >> 4;                    // k-group 0..3
  const int q0 = blockIdx.x * 64;
  const int bh = blockIdx.y;
  const int b = bh >> 4, h = bh & 15;
  const int hk = h >> 2;                       // GQA: kv head

  // Q fragments: A[row=lr][k = lk*8 + j (+32*ch)]
  const float* qrow = ql + ((size_t)bh * kS + q0 + w * 16 + lr) * kL;
  bf16x8 qf[2];
#pragma unroll
  for (int ch = 0; ch < 2; ++ch) {
    const int off = ch * 32 + lk * 8;
    qf[ch] = pack8(*(const float4*)(qrow + off),
                   *(const float4*)(qrow + off + 4));
  }

  f32x4 Of[4] = {};                            // O[cb]: row lk*4+r, col cb*16+lr
  float m_r[4], l_r[4];
#pragma unroll
  for (int r = 0; r < 4; ++r) { m_r[r] = -3.0e38f; l_r[r] = 0.f; }

  const size_t kvbase = (size_t)(b * kHKV + hk) * kS * kL;
  const int ntiles = q0 / 64 + 1;

  for (int t = 0; t < ntiles; ++t) {
    const int j0 = t * 64;
    __syncthreads();                           // prev tile's reads done
    // Stage K: row-major bf16, coalesced float4 reads, short4 writes.
    for (int i = tid; i < 64 * 16; i += 256) {
      const int r = i >> 4, c4 = (i & 15) << 2;
      const float4 kv = *(const float4*)(kl + kvbase + (size_t)(j0 + r) * kL + c4);
      *(short4*)&Kt[r * LDK + c4] =
          make_short4(f2bf(kv.x), f2bf(kv.y), f2bf(kv.z), f2bf(kv.w));
    }
    // Stage V^T: thread gathers 4 keys for one latent col (coalesced reads),
    // writes short4 along the key dim of Vt.
    for (int i = tid; i < 64 * 16; i += 256) {
      const int c = i & 63;                    // latent index
      const int r0 = (i >> 6) << 2;            // key base
      const float v0 = vl[kvbase + (size_t)(j0 + r0 + 0) * kL + c];
      const float v1 = vl[kvbase + (size_t)(j0 + r0 + 1) * kL + c];
      const float v2 = vl[kvbase + (size_t)(j0 + r0 + 2) * kL + c];
      const float v3 = vl[kvbase + (size_t)(j0 + r0 + 3) * kL + c];
      *(short4*)&Vt[c * LDK + r0] =
          make_short4(f2bf(v0), f2bf(v1), f2bf(v2), f2bf(v3));
    }
    __syncthreads();

    // S = Q @ K^T  (4 col-blocks x 2 k-chunks)
    f32x4 Sf[4];
#pragma unroll
    for (int cb = 0; cb < 4; ++cb) {
      f32x4 acc = {};
#pragma unroll
      for (int ch = 0; ch < 2; ++ch) {
        const bf16x8 kf = *(const bf16x8*)&Kt[(cb * 16 + lr) * LDK + ch * 32 + lk * 8];
        acc = __builtin_amdgcn_mfma_f32_16x16x32_bf16(qf[ch], kf, acc, 0, 0, 0);
      }
      Sf[cb] = acc;
    }

    // scale + causal mask (diagonal tile only) + row max
    const bool diag = (j0 == q0);
    float mt[4] = {-3.0e38f, -3.0e38f, -3.0e38f, -3.0e38f};
#pragma unroll
    for (int cb = 0; cb < 4; ++cb)
#pragma unroll
      for (int r = 0; r < 4; ++r) {
        float s = Sf[cb][r] * 0.125f;
        if (diag && (cb * 16 + lr) > (w * 16 + lk * 4 + r)) s = -3.0e38f;
        Sf[cb][r] = s;
        mt[r] = fmaxf(mt[r], s);
      }
#pragma unroll
    for (int d = 1; d < 16; d <<= 1)
#pragma unroll
      for (int r = 0; r < 4; ++r) mt[r] = fmaxf(mt[r], __shfl_xor(mt[r], d));

    // online-softmax update
    float corr[4];
#pragma unroll
    for (int r = 0; r < 4; ++r) {
      const float mnew = fmaxf(m_r[r], mt[r]);
      corr[r] = __expf(m_r[r] - mnew);
      m_r[r] = mnew;
      l_r[r] *= corr[r];
    }
    // P = exp(S - m): accumulate per-lane partial row sums, write bf16 to
    // wave-private LDS rows (row = w*16 + lk*4 + r, col = cb*16 + lr).
#pragma unroll
    for (int cb = 0; cb < 4; ++cb)
#pragma unroll
      for (int r = 0; r < 4; ++r) {
        const float p = __expf(Sf[cb][r] - m_r[r]);
        l_r[r] += p;
        Pt[(w * 16 + lk * 4 + r) * LDK + cb * 16 + lr] = f2bf(p);
      }
    // same-wave LDS write->read (cross-lane): drain before A-frag reads
    asm volatile("s_waitcnt lgkmcnt(0)" ::: "memory");

    // O = O*corr + P @ V   (A = P frag, B = V^T frag)
#pragma unroll
    for (int cb = 0; cb < 4; ++cb) {
      f32x4 acc = Of[cb];
#pragma unroll
      for (int r = 0; r < 4; ++r) acc[r] *= corr[r];
#pragma unroll
      for (int ch = 0; ch < 2; ++ch) {
        const bf16x8 pf = *(const bf16x8*)&Pt[(w * 16 + lr) * LDK + ch * 32 + lk * 8];
        const bf16x8 vf = *(const bf16x8*)&Vt[(cb * 16 + lr) * LDK + ch * 32 + lk * 8];
        acc = __builtin_amdgcn_mfma_f32_16x16x32_bf16(pf, vf, acc, 0, 0, 0);
      }
      Of[cb] = acc;
    }
  }

  // final cross-lane lsum reduce (16-lane groups), then write O/lsum
#pragma unroll
  for (int d = 1; d < 16; d <<= 1)
#pragma unroll
    for (int r = 0; r < 4; ++r) l_r[r] += __shfl_xor(l_r[r], d);

#pragma unroll
  for (int r = 0; r < 4; ++r) {
    const float inv = 1.f / l_r[r];
    const size_t row = (size_t)(b * kS + q0 + w * 16 + lk * 4 + r) * (kH * kL);
#pragma unroll
    for (int cb = 0; cb < 4; ++cb)
      attn_out[row + h * kL + cb * 16 + lr] = Of[cb][r] * inv;
  }
}

// ---------------------------------------------------------------------------
extern "C" void kernel_launch(void* const* d_in, const int* in_sizes, int n_in,
                              void* d_out, int out_size, void* d_ws, size_t ws_size,
                              hipStream_t stream) {
  const float* x    = (const float*)d_in[0];
  const int*   pos  = (const int*)d_in[1];
  const float* Wq   = (const float*)d_in[3];
  const float* Wk   = (const float*)d_in[4];
  const float* Wv   = (const float*)d_in[5];
  const float* Wql  = (const float*)d_in[6];
  const float* Wkl  = (const float*)d_in[7];
  const float* Wvl  = (const float*)d_in[8];
  const float* Wo   = (const float*)d_in[9];
  float* out = (float*)d_out;

  float* q_buf = (float*)d_out;                       // 4096 * 2048 scratch
  float* ws    = (float*)d_ws;
  float* k_buf = ws;                                  // 4096 * 512
  float* v_buf = k_buf + (size_t)kTok * kHKV * kD;    // 4096 * 512
  float* q_l   = v_buf + (size_t)kTok * kHKV * kD;    // 2*16*2048*64
  float* k_l   = q_l   + (size_t)kB * kH * kS * kL;
  float* v_l   = k_l   + (size_t)kB * kHKV * kS * kL;
  float* attn  = v_l   + (size_t)kB * kHKV * kS * kL; // 4096 * 1024

  // 1) Projections
  gemm64<false><<<dim3(kH * kD / 64, kTok / 64), 256, 0, stream>>>(
      x, Wq, q_buf, kTok, kH * kD, kHID);
  gemm64<false><<<dim3(kHKV * kD / 64, kTok / 64), 256, 0, stream>>>(
      x, Wk, k_buf, kTok, kHKV * kD, kHID);
  gemm64<false><<<dim3(kHKV * kD / 64, kTok / 64), 256, 0, stream>>>(
      x, Wv, v_buf, kTok, kHKV * kD, kHID);

  // 2) RoPE (in-place)
  {
    const int totq = kTok * kH * 64;
    rope_kernel<<<(totq + 255) / 256, 256, 0, stream>>>(q_buf, pos, kH, totq);
    const int totk = kTok * kHKV * 64;
    rope_kernel<<<(totk + 255) / 256, 256, 0, stream>>>(k_buf, pos, kHKV, totk);
  }

  // 3) Latent projections
  latent_proj<<<dim3(kS / 64, kB * kH), 256, 0, stream>>>(q_buf, Wql, q_l, kH);
  latent_proj<<<dim3(kS / 64, kB * kHKV), 256, 0, stream>>>(k_buf, Wkl, k_l, kHKV);
  latent_proj<<<dim3(kS / 64, kB * kHKV), 256, 0, stream>>>(v_buf, Wvl, v_l, kHKV);

  // 4) MFMA flash attention -> attn in [token][h*64+l] layout
  flash_attn_mfma<<<dim3(kS / 64, kB * kH), 256, 0, stream>>>(q_l, k_l, v_l, attn);

  // 5) Output GEMM: (4096 x 1024) @ Wo[remapped rows] -> d_out
  gemm64<true><<<dim3(kHID / 64, kTok / 64), 256, 0, stream>>>(
      attn, Wo, out, kTok, kHID, kH * kL);
}

// Round 3
// 417.575 us; speedup vs baseline: 7.1806x; 3.1521x over previous
//
#include <hip/hip_runtime.h>
#include <cstddef>

// Problem constants
constexpr int kB   = 2;
constexpr int kS   = 2048;
constexpr int kHID = 2048;
constexpr int kH   = 16;
constexpr int kHKV = 4;
constexpr int kD   = 128;
constexpr int kL   = 64;
constexpr int kTok = kB * kS;             // 4096 tokens
constexpr int kNQKV = kH * kD + 2 * kHKV * kD;  // 3072 fused QKV cols

typedef __attribute__((ext_vector_type(8))) short bf16x8;
typedef __attribute__((ext_vector_type(4))) float f32x4;

static __device__ __forceinline__ short f2bf(float f) {
  union { float f; unsigned u; } v{f};
  const unsigned r = (v.u + 0x7fff + ((v.u >> 16) & 1)) >> 16;
  return (short)r;
}

static __device__ __forceinline__ bf16x8 pack8(float4 a, float4 b) {
  bf16x8 r;
  r[0] = f2bf(a.x); r[1] = f2bf(a.y); r[2] = f2bf(a.z); r[3] = f2bf(a.w);
  r[4] = f2bf(b.x); r[5] = f2bf(b.y); r[6] = f2bf(b.z); r[7] = f2bf(b.w);
  return r;
}

// async global->LDS, 16B per lane. LDS dest must be wave-uniform base + lane*16.
typedef __attribute__((address_space(3))) void       lds_void;
typedef __attribute__((address_space(1))) const void gm_void;
static __device__ __forceinline__ void gload16(const void* g, void* l) {
  __builtin_amdgcn_global_load_lds((gm_void*)g, (lds_void*)l, 16, 0, 0);
}

// ---------------------------------------------------------------------------
// fp32 -> bf16 elementwise (8 elems / thread)
// ---------------------------------------------------------------------------
__global__ __launch_bounds__(256) void cvt_bf16(const float* __restrict__ in,
                                                short* __restrict__ out, int n8) {
  const int i = blockIdx.x * 256 + threadIdx.x;
  if (i >= n8) return;
  const float4 a = *(const float4*)&in[i * 8];
  const float4 b = *(const float4*)&in[i * 8 + 4];
  *(bf16x8*)&out[i * 8] = pack8(a, b);
}

// ---------------------------------------------------------------------------
// Transpose + convert: out[row_off + n][k] (bf16, ld=out_ld) = in[rmap(k)][n]
// in: fp32 [*][Nin] row-major. grid = (Nin/64, Krange/64), 256 threads.
// REMAP: k -> (k>>6)*128 + (k&63)   (skip Wo's zero-padded rows)
// ---------------------------------------------------------------------------
template <bool REMAP>
__global__ __launch_bounds__(256) void transpose_cvt(
    const float* __restrict__ in, short* __restrict__ out,
    int Nin, int out_ld, int row_off) {
  __shared__ float T[64][65];
  const int tid = threadIdx.x;
  const int k0 = blockIdx.y * 64, n0 = blockIdx.x * 64;
  const int rr = tid >> 4;          // 0..15
  const int cc = tid & 15;          // 0..15
#pragma unroll
  for (int ii = 0; ii < 4; ++ii) {
    const int kr = rr + ii * 16;
    int gr = k0 + kr;
    if (REMAP) gr = ((gr >> 6) << 7) + (gr & 63);
    const float4 v = *(const float4*)&in[(size_t)gr * Nin + n0 + cc * 4];
    T[kr][cc * 4 + 0] = v.x; T[kr][cc * 4 + 1] = v.y;
    T[kr][cc * 4 + 2] = v.z; T[kr][cc * 4 + 3] = v.w;
  }
  __syncthreads();
#pragma unroll
  for (int ii = 0; ii < 4; ++ii) {
    const int n = rr + ii * 16;
    const short4 s4 = make_short4(f2bf(T[cc * 4 + 0][n]), f2bf(T[cc * 4 + 1][n]),
                                  f2bf(T[cc * 4 + 2][n]), f2bf(T[cc * 4 + 3][n]));
    *(short4*)&out[(size_t)(row_off + n0 + n) * out_ld + k0 + cc * 4] = s4;
  }
}

// ---------------------------------------------------------------------------
// bf16 MFMA GEMM, m97 structure: C[M,N] = A[M,K] @ Bt[N,K]^T.
// 128x128 tile, BK=32, 256 threads (2x2 waves, 4x4 16x16x32 frags each),
// global_load_lds(16B) staging into linear LDS, 2 barriers / K-step.
// EPI=0: C0 fp32 [M][N].  EPI=1: QKV split by block col (block-uniform).
// ---------------------------------------------------------------------------
template <int EPI>
__global__ __launch_bounds__(256) void gemm_mfma(
    const short* __restrict__ A, const short* __restrict__ Bt,
    float* __restrict__ C0, float* __restrict__ C1, float* __restrict__ C2,
    int M, int N, int K) {
  __shared__ short As[128 * 32];
  __shared__ short Bs[128 * 32];
  const int tid = threadIdx.x;
  const int l = tid & 63, w = tid >> 6;
  const int lr = l & 15, lk = l >> 4;
  const int wm = w >> 1, wn = w & 1;
  const int row0 = blockIdx.y * 128, col0 = blockIdx.x * 128;

  f32x4 acc[4][4] = {};

  for (int k0 = 0; k0 < K; k0 += 32) {
    __syncthreads();
#pragma unroll
    for (int j = 0; j < 2; ++j) {
      const int idx = j * 256 + tid;
      const int r = idx >> 2, c = idx & 3;
      gload16(A  + (size_t)(row0 + r) * K + k0 + c * 8, &As[idx * 8]);
      gload16(Bt + (size_t)(col0 + r) * K + k0 + c * 8, &Bs[idx * 8]);
    }
    __syncthreads();
    bf16x8 af[4], bfr[4];
#pragma unroll
    for (int m = 0; m < 4; ++m)
      af[m] = *(const bf16x8*)&As[(wm * 64 + m * 16 + lr) * 32 + lk * 8];
#pragma unroll
    for (int n = 0; n < 4; ++n)
      bfr[n] = *(const bf16x8*)&Bs[(wn * 64 + n * 16 + lr) * 32 + lk * 8];
#pragma unroll
    for (int m = 0; m < 4; ++m)
#pragma unroll
      for (int n = 0; n < 4; ++n)
        acc[m][n] = __builtin_amdgcn_mfma_f32_16x16x32_bf16(af[m], bfr[n],
                                                            acc[m][n], 0, 0, 0);
  }

  // epilogue: D row = lk*4 + reg, col = lr (within each 16x16 fragment)
  float* dst; int ld, cb;
  if (EPI == 0) { dst = C0; ld = N; cb = col0; }
  else if (col0 < 2048)      { dst = C0; ld = 2048; cb = col0; }
  else if (col0 < 2560)      { dst = C1; ld = 512;  cb = col0 - 2048; }
  else                       { dst = C2; ld = 512;  cb = col0 - 2560; }
  const int crow0 = row0 + wm * 64 + lk * 4;
  const int ccol0 = cb + wn * 64 + lr;
#pragma unroll
  for (int m = 0; m < 4; ++m)
#pragma unroll
    for (int n = 0; n < 4; ++n)
#pragma unroll
      for (int rr = 0; rr < 4; ++rr)
        dst[(size_t)(crow0 + m * 16 + rr) * ld + ccol0 + n * 16] = acc[m][n][rr];
}

// ---------------------------------------------------------------------------
// RoPE in-place on fp32 buf [token][h][128] (rotate-half pairing).
// ---------------------------------------------------------------------------
__global__ void rope_kernel(float* __restrict__ buf,
                            const int* __restrict__ pos_ids,
                            int nh, int total) {
  const int idx = blockIdx.x * 256 + threadIdx.x;
  if (idx >= total) return;
  const int i = idx & 63;
  const int h = (idx >> 6) % nh;
  const int t = idx / (64 * nh);
  const float p = (float)pos_ids[t];
  const float inv_freq = expf(-(float)i * (9.210340371976184f / 64.0f));
  const float ang = p * inv_freq;
  const float c = cosf(ang);
  const float sn = sinf(ang);
  float* bp = buf + ((size_t)t * nh + h) * kD;
  const float t1 = bp[i];
  const float t2 = bp[i + 64];
  bp[i]      = t1 * c - t2 * sn;
  bp[i + 64] = t2 * c + t1 * sn;
}

// ---------------------------------------------------------------------------
// Latent projection -> bf16: out[(b*nh+h)][s][64] = in[(b,s,h,:128)] @ W
// ---------------------------------------------------------------------------
__global__ __launch_bounds__(256) void latent_proj(const float* __restrict__ in,
                                                   const float* __restrict__ W,
                                                   short* __restrict__ out,
                                                   int nh) {
  __shared__ float Ws[kD][kL];
  const int tid = threadIdx.x;
  for (int i = tid; i < kD * kL; i += 256) Ws[i >> 6][i & 63] = W[i];
  __syncthreads();
  const int bh = blockIdx.y;
  const int b = bh / nh, h = bh % nh;
  const int s0 = blockIdx.x * 64;
  const int lcol = tid & 63;
  const int sr = tid >> 6;
  for (int s = s0 + sr; s < s0 + 64; s += 4) {
    const float* ip = in + ((size_t)(b * kS + s) * nh + h) * kD;
    float acc = 0.f;
    for (int d0 = 0; d0 < kD; d0 += 4) {
      const float4 iv = *reinterpret_cast<const float4*>(ip + d0);
      acc += iv.x * Ws[d0][lcol] + iv.y * Ws[d0 + 1][lcol] +
             iv.z * Ws[d0 + 2][lcol] + iv.w * Ws[d0 + 3][lcol];
    }
    out[((size_t)(b * nh + h) * kS + s) * kL + lcol] = f2bf(acc);
  }
}

// ---------------------------------------------------------------------------
// MFMA flash attention, causal, bf16 in / bf16 out (fp32 accumulate).
// Block = 256 threads (4 waves) = 64 q rows of one (b,h); grid (S/64, B*H).
// ---------------------------------------------------------------------------
__global__ __launch_bounds__(256) void flash_attn_mfma(
    const short* __restrict__ ql, const short* __restrict__ kl,
    const short* __restrict__ vl, short* __restrict__ attn_out) {
  constexpr int LDK = 72;                      // 64 + 8 pad (bf16 elems)
  __shared__ short Kt[64 * LDK];
  __shared__ short Vt[64 * LDK];
  __shared__ short Pt[64 * LDK];

  const int tid = threadIdx.x;
  const int lane = tid & 63;
  const int w = tid >> 6;
  const int lr = lane & 15;
  const int lk = lane >> 4;
  const int q0 = blockIdx.x * 64;
  const int bh = blockIdx.y;
  const int b = bh >> 4, h = bh & 15;
  const int hk = h >> 2;

  const short* qrow = ql + ((size_t)bh * kS + q0 + w * 16 + lr) * kL;
  bf16x8 qf[2];
#pragma unroll
  for (int ch = 0; ch < 2; ++ch)
    qf[ch] = *(const bf16x8*)(qrow + ch * 32 + lk * 8);

  f32x4 Of[4] = {};
  float m_r[4], l_r[4];
#pragma unroll
  for (int r = 0; r < 4; ++r) { m_r[r] = -3.0e38f; l_r[r] = 0.f; }

  const size_t kvbase = (size_t)(b * kHKV + hk) * kS * kL;
  const int ntiles = q0 / 64 + 1;

  for (int t = 0; t < ntiles; ++t) {
    const int j0 = t * 64;
    __syncthreads();
    // Stage K rows (bf16, 16B chunks)
    for (int i = tid; i < 64 * 8; i += 256) {
      const int r = i >> 3, c8 = (i & 7) << 3;
      *(bf16x8*)&Kt[r * LDK + c8] =
          *(const bf16x8*)(kl + kvbase + (size_t)(j0 + r) * kL + c8);
    }
    // Stage V^T (gather 4 keys per latent col)
    for (int i = tid; i < 64 * 16; i += 256) {
      const int c = i & 63;
      const int r0 = (i >> 6) << 2;
      const short v0 = vl[kvbase + (size_t)(j0 + r0 + 0) * kL + c];
      const short v1 = vl[kvbase + (size_t)(j0 + r0 + 1) * kL + c];
      const short v2 = vl[kvbase + (size_t)(j0 + r0 + 2) * kL + c];
      const short v3 = vl[kvbase + (size_t)(j0 + r0 + 3) * kL + c];
      *(short4*)&Vt[c * LDK + r0] = make_short4(v0, v1, v2, v3);
    }
    __syncthreads();

    f32x4 Sf[4];
#pragma unroll
    for (int cb = 0; cb < 4; ++cb) {
      f32x4 acc = {};
#pragma unroll
      for (int ch = 0; ch < 2; ++ch) {
        const bf16x8 kf = *(const bf16x8*)&Kt[(cb * 16 + lr) * LDK + ch * 32 + lk * 8];
        acc = __builtin_amdgcn_mfma_f32_16x16x32_bf16(qf[ch], kf, acc, 0, 0, 0);
      }
      Sf[cb] = acc;
    }

    const bool diag = (j0 == q0);
    float mt[4] = {-3.0e38f, -3.0e38f, -3.0e38f, -3.0e38f};
#pragma unroll
    for (int cb = 0; cb < 4; ++cb)
#pragma unroll
      for (int r = 0; r < 4; ++r) {
        float s = Sf[cb][r] * 0.125f;
        if (diag && (cb * 16 + lr) > (w * 16 + lk * 4 + r)) s = -3.0e38f;
        Sf[cb][r] = s;
        mt[r] = fmaxf(mt[r], s);
      }
#pragma unroll
    for (int d = 1; d < 16; d <<= 1)
#pragma unroll
      for (int r = 0; r < 4; ++r) mt[r] = fmaxf(mt[r], __shfl_xor(mt[r], d));

    float corr[4];
#pragma unroll
    for (int r = 0; r < 4; ++r) {
      const float mnew = fmaxf(m_r[r], mt[r]);
      corr[r] = __expf(m_r[r] - mnew);
      m_r[r] = mnew;
      l_r[r] *= corr[r];
    }
#pragma unroll
    for (int cb = 0; cb < 4; ++cb)
#pragma unroll
      for (int r = 0; r < 4; ++r) {
        const float p = __expf(Sf[cb][r] - m_r[r]);
        l_r[r] += p;
        Pt[(w * 16 + lk * 4 + r) * LDK + cb * 16 + lr] = f2bf(p);
      }
    asm volatile("s_waitcnt lgkmcnt(0)" ::: "memory");

#pragma unroll
    for (int cb = 0; cb < 4; ++cb) {
      f32x4 acc = Of[cb];
#pragma unroll
      for (int r = 0; r < 4; ++r) acc[r] *= corr[r];
#pragma unroll
      for (int ch = 0; ch < 2; ++ch) {
        const bf16x8 pf = *(const bf16x8*)&Pt[(w * 16 + lr) * LDK + ch * 32 + lk * 8];
        const bf16x8 vf = *(const bf16x8*)&Vt[(cb * 16 + lr) * LDK + ch * 32 + lk * 8];
        acc = __builtin_amdgcn_mfma_f32_16x16x32_bf16(pf, vf, acc, 0, 0, 0);
      }
      Of[cb] = acc;
    }
  }

#pragma unroll
  for (int d = 1; d < 16; d <<= 1)
#pragma unroll
    for (int r = 0; r < 4; ++r) l_r[r] += __shfl_xor(l_r[r], d);

#pragma unroll
  for (int r = 0; r < 4; ++r) {
    const float inv = 1.f / l_r[r];
    const size_t row = (size_t)(b * kS + q0 + w * 16 + lk * 4 + r) * (kH * kL);
#pragma unroll
    for (int cb = 0; cb < 4; ++cb)
      attn_out[row + h * kL + cb * 16 + lr] = f2bf(Of[cb][r] * inv);
  }
}

// ---------------------------------------------------------------------------
extern "C" void kernel_launch(void* const* d_in, const int* in_sizes, int n_in,
                              void* d_out, int out_size, void* d_ws, size_t ws_size,
                              hipStream_t stream) {
  const float* x    = (const float*)d_in[0];
  const int*   pos  = (const int*)d_in[1];
  const float* Wq   = (const float*)d_in[3];
  const float* Wk   = (const float*)d_in[4];
  const float* Wv   = (const float*)d_in[5];
  const float* Wql  = (const float*)d_in[6];
  const float* Wkl  = (const float*)d_in[7];
  const float* Wvl  = (const float*)d_in[8];
  const float* Wo   = (const float*)d_in[9];
  float* out = (float*)d_out;

  // Workspace carve
  char* p = (char*)d_ws;
  short* x_bf  = (short*)p; p += (size_t)kTok * kHID * 2;        // 16 MB
  short* Wqkv  = (short*)p; p += (size_t)kNQKV * kHID * 2;       // 12.6 MB
  short* WoT   = (short*)p; p += (size_t)kHID * (kH * kL) * 2;   // 4 MB
  float* k_buf = (float*)p; p += (size_t)kTok * kHKV * kD * 4;   // 8 MB
  float* v_buf = (float*)p; p += (size_t)kTok * kHKV * kD * 4;   // 8 MB
  short* q_l   = (short*)p; p += (size_t)kB * kH * kS * kL * 2;  // 8 MB
  short* k_l   = (short*)p; p += (size_t)kB * kHKV * kS * kL * 2;
  short* v_l   = (short*)p; p += (size_t)kB * kHKV * kS * kL * 2;
  short* attn  = (short*)p;                                      // 8 MB
  float* q_buf = (float*)d_out;   // scratch until final GEMM

  // 0) dtype prep: x -> bf16; fused transposed bf16 weights
  cvt_bf16<<<kTok * kHID / 8 / 256, 256, 0, stream>>>(x, x_bf, kTok * kHID / 8);
  transpose_cvt<false><<<dim3(kH * kD / 64, kHID / 64), 256, 0, stream>>>(
      Wq, Wqkv, kH * kD, kHID, 0);
  transpose_cvt<false><<<dim3(kHKV * kD / 64, kHID / 64), 256, 0, stream>>>(
      Wk, Wqkv, kHKV * kD, kHID, kH * kD);
  transpose_cvt<false><<<dim3(kHKV * kD / 64, kHID / 64), 256, 0, stream>>>(
      Wv, Wqkv, kHKV * kD, kHID, kH * kD + kHKV * kD);
  transpose_cvt<true><<<dim3(kHID / 64, (kH * kL) / 64), 256, 0, stream>>>(
      Wo, WoT, kHID, kH * kL, 0);

  // 1) Fused QKV projection (MFMA): [4096x2048] @ [2048x3072]
  gemm_mfma<1><<<dim3(kNQKV / 128, kTok / 128), 256, 0, stream>>>(
      x_bf, Wqkv, q_buf, k_buf, v_buf, kTok, kNQKV, kHID);

  // 2) RoPE (in-place, fp32)
  {
    const int totq = kTok * kH * 64;
    rope_kernel<<<(totq + 255) / 256, 256, 0, stream>>>(q_buf, pos, kH, totq);
    const int totk = kTok * kHKV * 64;
    rope_kernel<<<(totk + 255) / 256, 256, 0, stream>>>(k_buf, pos, kHKV, totk);
  }

  // 3) Latent projections -> bf16
  latent_proj<<<dim3(kS / 64, kB * kH), 256, 0, stream>>>(q_buf, Wql, q_l, kH);
  latent_proj<<<dim3(kS / 64, kB * kHKV), 256, 0, stream>>>(k_buf, Wkl, k_l, kHKV);
  latent_proj<<<dim3(kS / 64, kB * kHKV), 256, 0, stream>>>(v_buf, Wvl, v_l, kHKV);

  // 4) MFMA flash attention -> bf16 attn [token][h*64+l]
  flash_attn_mfma<<<dim3(kS / 64, kB * kH), 256, 0, stream>>>(q_l, k_l, v_l, attn);

  // 5) Output GEMM (MFMA): [4096x1024] @ WoT^T -> d_out [4096x2048]
  gemm_mfma<0><<<dim3(kHID / 128, kTok / 128), 256, 0, stream>>>(
      attn, WoT, out, nullptr, nullptr, kTok, kHID, kH * kL);
}

// Round 4
// 390.444 us; speedup vs baseline: 7.6795x; 1.0695x over previous
//
#include <hip/hip_runtime.h>
#include <cstddef>

// Problem constants
constexpr int kB   = 2;
constexpr int kS   = 2048;
constexpr int kHID = 2048;
constexpr int kH   = 16;
constexpr int kHKV = 4;
constexpr int kD   = 128;
constexpr int kL   = 64;
constexpr int kTok = kB * kS;             // 4096 tokens
constexpr int kNQKV = kH * kD + 2 * kHKV * kD;  // 3072 fused QKV cols

typedef __attribute__((ext_vector_type(8))) short bf16x8;
typedef __attribute__((ext_vector_type(4))) float f32x4;

static __device__ __forceinline__ short f2bf(float f) {
  union { float f; unsigned u; } v{f};
  const unsigned r = (v.u + 0x7fff + ((v.u >> 16) & 1)) >> 16;
  return (short)r;
}

static __device__ __forceinline__ bf16x8 pack8(float4 a, float4 b) {
  bf16x8 r;
  r[0] = f2bf(a.x); r[1] = f2bf(a.y); r[2] = f2bf(a.z); r[3] = f2bf(a.w);
  r[4] = f2bf(b.x); r[5] = f2bf(b.y); r[6] = f2bf(b.z); r[7] = f2bf(b.w);
  return r;
}

// async global->LDS, 16B per lane. LDS dest must be wave-uniform base + lane*16.
typedef __attribute__((address_space(3))) void       lds_void;
typedef __attribute__((address_space(1))) const void gm_void;
static __device__ __forceinline__ void gload16(const void* g, void* l) {
  __builtin_amdgcn_global_load_lds((gm_void*)g, (lds_void*)l, 16, 0, 0);
}

// ---------------------------------------------------------------------------
// fp32 -> bf16 elementwise (8 elems / thread)
// ---------------------------------------------------------------------------
__global__ __launch_bounds__(256) void cvt_bf16(const float* __restrict__ in,
                                                short* __restrict__ out, int n8) {
  const int i = blockIdx.x * 256 + threadIdx.x;
  if (i >= n8) return;
  const float4 a = *(const float4*)&in[i * 8];
  const float4 b = *(const float4*)&in[i * 8 + 4];
  *(bf16x8*)&out[i * 8] = pack8(a, b);
}

// ---------------------------------------------------------------------------
// Transpose + convert: out[row_off + n][k] (bf16, ld=out_ld) = in[rmap(k)][n]
// REMAP: k -> (k>>6)*128 + (k&63)   (skip Wo's zero-padded rows)
// ---------------------------------------------------------------------------
template <bool REMAP>
__global__ __launch_bounds__(256) void transpose_cvt(
    const float* __restrict__ in, short* __restrict__ out,
    int Nin, int out_ld, int row_off) {
  __shared__ float T[64][65];
  const int tid = threadIdx.x;
  const int k0 = blockIdx.y * 64, n0 = blockIdx.x * 64;
  const int rr = tid >> 4;          // 0..15
  const int cc = tid & 15;          // 0..15
#pragma unroll
  for (int ii = 0; ii < 4; ++ii) {
    const int kr = rr + ii * 16;
    int gr = k0 + kr;
    if (REMAP) gr = ((gr >> 6) << 7) + (gr & 63);
    const float4 v = *(const float4*)&in[(size_t)gr * Nin + n0 + cc * 4];
    T[kr][cc * 4 + 0] = v.x; T[kr][cc * 4 + 1] = v.y;
    T[kr][cc * 4 + 2] = v.z; T[kr][cc * 4 + 3] = v.w;
  }
  __syncthreads();
#pragma unroll
  for (int ii = 0; ii < 4; ++ii) {
    const int n = rr + ii * 16;
    const short4 s4 = make_short4(f2bf(T[cc * 4 + 0][n]), f2bf(T[cc * 4 + 1][n]),
                                  f2bf(T[cc * 4 + 2][n]), f2bf(T[cc * 4 + 3][n]));
    *(short4*)&out[(size_t)(row_off + n0 + n) * out_ld + k0 + cc * 4] = s4;
  }
}

// ---------------------------------------------------------------------------
// bf16 MFMA GEMM, m97 structure: C[M,N] = A[M,K] @ Bt[N,K]^T.
// ---------------------------------------------------------------------------
template <int EPI>
__global__ __launch_bounds__(256) void gemm_mfma(
    const short* __restrict__ A, const short* __restrict__ Bt,
    float* __restrict__ C0, float* __restrict__ C1, float* __restrict__ C2,
    int M, int N, int K) {
  __shared__ short As[128 * 32];
  __shared__ short Bs[128 * 32];
  const int tid = threadIdx.x;
  const int l = tid & 63, w = tid >> 6;
  const int lr = l & 15, lk = l >> 4;
  const int wm = w >> 1, wn = w & 1;
  const int row0 = blockIdx.y * 128, col0 = blockIdx.x * 128;

  f32x4 acc[4][4] = {};

  for (int k0 = 0; k0 < K; k0 += 32) {
    __syncthreads();
#pragma unroll
    for (int j = 0; j < 2; ++j) {
      const int idx = j * 256 + tid;
      const int r = idx >> 2, c = idx & 3;
      gload16(A  + (size_t)(row0 + r) * K + k0 + c * 8, &As[idx * 8]);
      gload16(Bt + (size_t)(col0 + r) * K + k0 + c * 8, &Bs[idx * 8]);
    }
    __syncthreads();
    bf16x8 af[4], bfr[4];
#pragma unroll
    for (int m = 0; m < 4; ++m)
      af[m] = *(const bf16x8*)&As[(wm * 64 + m * 16 + lr) * 32 + lk * 8];
#pragma unroll
    for (int n = 0; n < 4; ++n)
      bfr[n] = *(const bf16x8*)&Bs[(wn * 64 + n * 16 + lr) * 32 + lk * 8];
#pragma unroll
    for (int m = 0; m < 4; ++m)
#pragma unroll
      for (int n = 0; n < 4; ++n)
        acc[m][n] = __builtin_amdgcn_mfma_f32_16x16x32_bf16(af[m], bfr[n],
                                                            acc[m][n], 0, 0, 0);
  }

  float* dst; int ld, cb;
  if (EPI == 0) { dst = C0; ld = N; cb = col0; }
  else if (col0 < 2048)      { dst = C0; ld = 2048; cb = col0; }
  else if (col0 < 2560)      { dst = C1; ld = 512;  cb = col0 - 2048; }
  else                       { dst = C2; ld = 512;  cb = col0 - 2560; }
  const int crow0 = row0 + wm * 64 + lk * 4;
  const int ccol0 = cb + wn * 64 + lr;
#pragma unroll
  for (int m = 0; m < 4; ++m)
#pragma unroll
    for (int n = 0; n < 4; ++n)
#pragma unroll
      for (int rr = 0; rr < 4; ++rr)
        dst[(size_t)(crow0 + m * 16 + rr) * ld + ccol0 + n * 16] = acc[m][n][rr];
}

// ---------------------------------------------------------------------------
// RoPE in-place on fp32 buf [token][h][128] (rotate-half pairing).
// ---------------------------------------------------------------------------
__global__ void rope_kernel(float* __restrict__ buf,
                            const int* __restrict__ pos_ids,
                            int nh, int total) {
  const int idx = blockIdx.x * 256 + threadIdx.x;
  if (idx >= total) return;
  const int i = idx & 63;
  const int h = (idx >> 6) % nh;
  const int t = idx / (64 * nh);
  const float p = (float)pos_ids[t];
  const float inv_freq = expf(-(float)i * (9.210340371976184f / 64.0f));
  const float ang = p * inv_freq;
  const float c = cosf(ang);
  const float sn = sinf(ang);
  float* bp = buf + ((size_t)t * nh + h) * kD;
  const float t1 = bp[i];
  const float t2 = bp[i + 64];
  bp[i]      = t1 * c - t2 * sn;
  bp[i + 64] = t2 * c + t1 * sn;
}

// ---------------------------------------------------------------------------
// Latent projection -> bf16. W is pre-scaled by `scale` at LDS load.
// TR=false: out[(b*nh+h)][s][64] row-major.
// TR=true : out[(b*nh+h)][l][S]  (transposed: feeds flash V^T staging
//           with coalesced rows). LDS round-trip transpose per 64-token tile.
// ---------------------------------------------------------------------------
template <bool TR>
__global__ __launch_bounds__(256) void latent_proj(const float* __restrict__ in,
                                                   const float* __restrict__ W,
                                                   short* __restrict__ out,
                                                   int nh, float scale) {
  __shared__ float Ws[kD][kL];
  __shared__ short T[64][66];
  const int tid = threadIdx.x;
  for (int i = tid; i < kD * kL; i += 256) Ws[i >> 6][i & 63] = W[i] * scale;
  __syncthreads();
  const int bh = blockIdx.y;
  const int b = bh / nh, h = bh % nh;
  const int s0 = blockIdx.x * 64;
  const int lcol = tid & 63;
  const int sr = tid >> 6;
  for (int s = s0 + sr; s < s0 + 64; s += 4) {
    const float* ip = in + ((size_t)(b * kS + s) * nh + h) * kD;
    float acc = 0.f;
    for (int d0 = 0; d0 < kD; d0 += 4) {
      const float4 iv = *reinterpret_cast<const float4*>(ip + d0);
      acc += iv.x * Ws[d0][lcol] + iv.y * Ws[d0 + 1][lcol] +
             iv.z * Ws[d0 + 2][lcol] + iv.w * Ws[d0 + 3][lcol];
    }
    if (TR) T[s - s0][lcol] = f2bf(acc);
    else out[((size_t)(b * nh + h) * kS + s) * kL + lcol] = f2bf(acc);
  }
  if (TR) {
    __syncthreads();
#pragma unroll
    for (int it = 0; it < 2; ++it) {
      const int idx = it * 256 + tid;
      const int ll = idx >> 3, s8 = (idx & 7) << 3;
      bf16x8 v;
#pragma unroll
      for (int i = 0; i < 8; ++i) v[i] = T[s8 + i][ll];
      *(bf16x8*)&out[((size_t)(b * nh + h) * kL + ll) * kS + s0 + s8] = v;
    }
  }
}

// ---------------------------------------------------------------------------
// MFMA flash attention, causal, bf16 in/out (fp32 accumulate).
// Block = 512 threads (8 waves) = 128 q rows of one (b,h); grid (S/128, B*H).
// Wave w owns q rows [q0+w*16, q0+w*16+16). Per 64-key tile: K rows and V^T
// rows (from the pre-transposed v_lT) staged coalesced (1 bf16x8 each per
// thread), QK^T and PV via mfma_f32_16x16x32_bf16. Scores arrive pre-scaled
// (1/sqrt(L) folded into Wql). Fully-masked tiles are skipped per-wave.
// ---------------------------------------------------------------------------
__global__ __launch_bounds__(512) void flash_attn_mfma(
    const short* __restrict__ ql, const short* __restrict__ kl,
    const short* __restrict__ vlT, short* __restrict__ attn_out) {
  constexpr int LDK = 72;                      // 64 + 8 pad (bf16 elems)
  __shared__ short Kt[64 * LDK];
  __shared__ short Vt[64 * LDK];               // row = latent l, col = key
  __shared__ short Pt[128 * LDK];

  const int tid = threadIdx.x;
  const int lane = tid & 63;
  const int w = tid >> 6;                      // wave 0..7
  const int lr = lane & 15;
  const int lk = lane >> 4;
  const int q0 = blockIdx.x * 128;
  const int bh = blockIdx.y;
  const int b = bh >> 4, h = bh & 15;
  const int hk = h >> 2;
  const int wrow = q0 + w * 16;                // wave's first q row (global)

  const short* qrow = ql + ((size_t)bh * kS + wrow + lr) * kL;
  bf16x8 qf[2];
  qf[0] = *(const bf16x8*)(qrow + lk * 8);
  qf[1] = *(const bf16x8*)(qrow + 32 + lk * 8);

  f32x4 Of[4] = {};
  float m_r[4], l_r[4];
#pragma unroll
  for (int r = 0; r < 4; ++r) { m_r[r] = -3.0e38f; l_r[r] = 0.f; }

  const size_t kbase = (size_t)(b * kHKV + hk) * kS * kL;   // k_l [s][64]
  const size_t vbase = (size_t)(b * kHKV + hk) * kL * kS;   // v_lT [l][S]
  const int ntiles = q0 / 64 + 2;
  const int sr = tid >> 3, sc8 = (tid & 7) << 3;            // staging coords

  for (int t = 0; t < ntiles; ++t) {
    const int j0 = t * 64;
    __syncthreads();                           // prev tile's reads done
    *(bf16x8*)&Kt[sr * LDK + sc8] =
        *(const bf16x8*)(kl + kbase + (size_t)(j0 + sr) * kL + sc8);
    *(bf16x8*)&Vt[sr * LDK + sc8] =
        *(const bf16x8*)(vlT + vbase + (size_t)sr * kS + j0 + sc8);
    __syncthreads();

    if (j0 > wrow + 15) continue;              // fully masked for this wave

    // S = Q @ K^T
    f32x4 Sf[4];
    __builtin_amdgcn_s_setprio(1);
#pragma unroll
    for (int cb = 0; cb < 4; ++cb) {
      f32x4 acc = {};
#pragma unroll
      for (int ch = 0; ch < 2; ++ch) {
        const bf16x8 kf = *(const bf16x8*)&Kt[(cb * 16 + lr) * LDK + ch * 32 + lk * 8];
        acc = __builtin_amdgcn_mfma_f32_16x16x32_bf16(qf[ch], kf, acc, 0, 0, 0);
      }
      Sf[cb] = acc;
    }
    __builtin_amdgcn_s_setprio(0);

    const bool diag = (j0 + 63 > wrow);
    float mt[4] = {-3.0e38f, -3.0e38f, -3.0e38f, -3.0e38f};
#pragma unroll
    for (int cb = 0; cb < 4; ++cb)
#pragma unroll
      for (int r = 0; r < 4; ++r) {
        float s = Sf[cb][r];
        if (diag && (j0 + cb * 16 + lr) > (wrow + lk * 4 + r)) s = -3.0e38f;
        Sf[cb][r] = s;
        mt[r] = fmaxf(mt[r], s);
      }
#pragma unroll
    for (int d = 1; d < 16; d <<= 1)
#pragma unroll
      for (int r = 0; r < 4; ++r) mt[r] = fmaxf(mt[r], __shfl_xor(mt[r], d));

    float corr[4];
#pragma unroll
    for (int r = 0; r < 4; ++r) {
      const float mnew = fmaxf(m_r[r], mt[r]);
      corr[r] = __expf(m_r[r] - mnew);
      m_r[r] = mnew;
      l_r[r] *= corr[r];
    }
#pragma unroll
    for (int cb = 0; cb < 4; ++cb)
#pragma unroll
      for (int r = 0; r < 4; ++r) {
        const float p = __expf(Sf[cb][r] - m_r[r]);
        l_r[r] += p;
        Pt[(w * 16 + lk * 4 + r) * LDK + cb * 16 + lr] = f2bf(p);
      }
    // same-wave LDS write->read (cross-lane): drain before A-frag reads
    asm volatile("s_waitcnt lgkmcnt(0)" ::: "memory");

    // O = O*corr + P @ V
    __builtin_amdgcn_s_setprio(1);
#pragma unroll
    for (int cb = 0; cb < 4; ++cb) {
      f32x4 acc = Of[cb];
#pragma unroll
      for (int r = 0; r < 4; ++r) acc[r] *= corr[r];
#pragma unroll
      for (int ch = 0; ch < 2; ++ch) {
        const bf16x8 pf = *(const bf16x8*)&Pt[(w * 16 + lr) * LDK + ch * 32 + lk * 8];
        const bf16x8 vf = *(const bf16x8*)&Vt[(cb * 16 + lr) * LDK + ch * 32 + lk * 8];
        acc = __builtin_amdgcn_mfma_f32_16x16x32_bf16(pf, vf, acc, 0, 0, 0);
      }
      Of[cb] = acc;
    }
    __builtin_amdgcn_s_setprio(0);
  }

#pragma unroll
  for (int d = 1; d < 16; d <<= 1)
#pragma unroll
    for (int r = 0; r < 4; ++r) l_r[r] += __shfl_xor(l_r[r], d);

#pragma unroll
  for (int r = 0; r < 4; ++r) {
    const float inv = 1.f / l_r[r];
    const size_t row = (size_t)(b * kS + wrow + lk * 4 + r) * (kH * kL);
#pragma unroll
    for (int cb = 0; cb < 4; ++cb)
      attn_out[row + h * kL + cb * 16 + lr] = f2bf(Of[cb][r] * inv);
  }
}

// ---------------------------------------------------------------------------
extern "C" void kernel_launch(void* const* d_in, const int* in_sizes, int n_in,
                              void* d_out, int out_size, void* d_ws, size_t ws_size,
                              hipStream_t stream) {
  const float* x    = (const float*)d_in[0];
  const int*   pos  = (const int*)d_in[1];
  const float* Wq   = (const float*)d_in[3];
  const float* Wk   = (const float*)d_in[4];
  const float* Wv   = (const float*)d_in[5];
  const float* Wql  = (const float*)d_in[6];
  const float* Wkl  = (const float*)d_in[7];
  const float* Wvl  = (const float*)d_in[8];
  const float* Wo   = (const float*)d_in[9];
  float* out = (float*)d_out;

  // Workspace carve
  char* p = (char*)d_ws;
  short* x_bf  = (short*)p; p += (size_t)kTok * kHID * 2;        // 16 MB
  short* Wqkv  = (short*)p; p += (size_t)kNQKV * kHID * 2;       // 12.6 MB
  short* WoT   = (short*)p; p += (size_t)kHID * (kH * kL) * 2;   // 4 MB
  float* k_buf = (float*)p; p += (size_t)kTok * kHKV * kD * 4;   // 8 MB
  float* v_buf = (float*)p; p += (size_t)kTok * kHKV * kD * 4;   // 8 MB
  short* q_l   = (short*)p; p += (size_t)kB * kH * kS * kL * 2;  // 8 MB
  short* k_l   = (short*)p; p += (size_t)kB * kHKV * kS * kL * 2;
  short* v_lT  = (short*)p; p += (size_t)kB * kHKV * kS * kL * 2;
  short* attn  = (short*)p;                                      // 8 MB
  float* q_buf = (float*)d_out;   // scratch until final GEMM

  // 0) dtype prep: x -> bf16; fused transposed bf16 weights
  cvt_bf16<<<kTok * kHID / 8 / 256, 256, 0, stream>>>(x, x_bf, kTok * kHID / 8);
  transpose_cvt<false><<<dim3(kH * kD / 64, kHID / 64), 256, 0, stream>>>(
      Wq, Wqkv, kH * kD, kHID, 0);
  transpose_cvt<false><<<dim3(kHKV * kD / 64, kHID / 64), 256, 0, stream>>>(
      Wk, Wqkv, kHKV * kD, kHID, kH * kD);
  transpose_cvt<false><<<dim3(kHKV * kD / 64, kHID / 64), 256, 0, stream>>>(
      Wv, Wqkv, kHKV * kD, kHID, kH * kD + kHKV * kD);
  transpose_cvt<true><<<dim3(kHID / 64, (kH * kL) / 64), 256, 0, stream>>>(
      Wo, WoT, kHID, kH * kL, 0);

  // 1) Fused QKV projection (MFMA)
  gemm_mfma<1><<<dim3(kNQKV / 128, kTok / 128), 256, 0, stream>>>(
      x_bf, Wqkv, q_buf, k_buf, v_buf, kTok, kNQKV, kHID);

  // 2) RoPE (in-place, fp32)
  {
    const int totq = kTok * kH * 64;
    rope_kernel<<<(totq + 255) / 256, 256, 0, stream>>>(q_buf, pos, kH, totq);
    const int totk = kTok * kHKV * 64;
    rope_kernel<<<(totk + 255) / 256, 256, 0, stream>>>(k_buf, pos, kHKV, totk);
  }

  // 3) Latent projections -> bf16 (1/sqrt(L) folded into q; V transposed)
  latent_proj<false><<<dim3(kS / 64, kB * kH), 256, 0, stream>>>(
      q_buf, Wql, q_l, kH, 0.125f);
  latent_proj<false><<<dim3(kS / 64, kB * kHKV), 256, 0, stream>>>(
      k_buf, Wkl, k_l, kHKV, 1.0f);
  latent_proj<true><<<dim3(kS / 64, kB * kHKV), 256, 0, stream>>>(
      v_buf, Wvl, v_lT, kHKV, 1.0f);

  // 4) MFMA flash attention (128 q-rows/block, 8 waves)
  flash_attn_mfma<<<dim3(kS / 128, kB * kH), 512, 0, stream>>>(
      q_l, k_l, v_lT, attn);

  // 5) Output GEMM (MFMA): [4096x1024] @ WoT^T -> d_out
  gemm_mfma<0><<<dim3(kHID / 128, kTok / 128), 256, 0, stream>>>(
      attn, WoT, out, nullptr, nullptr, kTok, kHID, kH * kL);
}

// Round 5
// 259.240 us; speedup vs baseline: 11.5663x; 1.5061x over previous
//
#include <hip/hip_runtime.h>
#include <cstddef>

// Problem constants
constexpr int kB   = 2;
constexpr int kS   = 2048;
constexpr int kHID = 2048;
constexpr int kH   = 16;
constexpr int kHKV = 4;
constexpr int kD   = 128;
constexpr int kL   = 64;
constexpr int kTok = kB * kS;             // 4096 tokens
constexpr int kNQKV = kH * kD + 2 * kHKV * kD;  // 3072 fused QKV cols

typedef __attribute__((ext_vector_type(8))) short bf16x8;
typedef __attribute__((ext_vector_type(4))) float f32x4;

static __device__ __forceinline__ short f2bf(float f) {
  union { float f; unsigned u; } v{f};
  const unsigned r = (v.u + 0x7fff + ((v.u >> 16) & 1)) >> 16;
  return (short)r;
}

static __device__ __forceinline__ bf16x8 pack8(float4 a, float4 b) {
  bf16x8 r;
  r[0] = f2bf(a.x); r[1] = f2bf(a.y); r[2] = f2bf(a.z); r[3] = f2bf(a.w);
  r[4] = f2bf(b.x); r[5] = f2bf(b.y); r[6] = f2bf(b.z); r[7] = f2bf(b.w);
  return r;
}

// async global->LDS, 16B per lane. LDS dest must be wave-uniform base + lane*16.
typedef __attribute__((address_space(3))) void       lds_void;
typedef __attribute__((address_space(1))) const void gm_void;
static __device__ __forceinline__ void gload16(const void* g, void* l) {
  __builtin_amdgcn_global_load_lds((gm_void*)g, (lds_void*)l, 16, 0, 0);
}

// ---------------------------------------------------------------------------
// fp32 -> bf16 elementwise (8 elems / thread)
// ---------------------------------------------------------------------------
__global__ __launch_bounds__(256) void cvt_bf16(const float* __restrict__ in,
                                                short* __restrict__ out, int n8) {
  const int i = blockIdx.x * 256 + threadIdx.x;
  if (i >= n8) return;
  const float4 a = *(const float4*)&in[i * 8];
  const float4 b = *(const float4*)&in[i * 8 + 4];
  *(bf16x8*)&out[i * 8] = pack8(a, b);
}

// ---------------------------------------------------------------------------
// Per-token RoPE cos/sin table: tbl[t][i] = cos(pos[t]*invf(i)),
// tbl[t][64+i] = sin(...)  for i in [0,64).
// ---------------------------------------------------------------------------
__global__ __launch_bounds__(256) void trig_table(const int* __restrict__ pos,
                                                  float* __restrict__ tbl) {
  const int idx = blockIdx.x * 256 + threadIdx.x;
  if (idx >= kTok * 64) return;
  const int i = idx & 63, t = idx >> 6;
  const float p = (float)pos[t];
  const float inv_freq = expf(-(float)i * (9.210340371976184f / 64.0f));
  const float ang = p * inv_freq;
  tbl[t * 128 + i]      = cosf(ang);
  tbl[t * 128 + 64 + i] = sinf(ang);
}

// ---------------------------------------------------------------------------
// Transpose + convert + scale: out[row_off+n][k] (bf16, ld) = in[rmap(k)][n]*scale
// REMAP: k -> (k>>6)*128 + (k&63)   (skip Wo's zero-padded rows)
// ---------------------------------------------------------------------------
template <bool REMAP>
__global__ __launch_bounds__(256) void transpose_cvt(
    const float* __restrict__ in, short* __restrict__ out,
    int Nin, int out_ld, int row_off, float scale) {
  __shared__ float T[64][65];
  const int tid = threadIdx.x;
  const int k0 = blockIdx.y * 64, n0 = blockIdx.x * 64;
  const int rr = tid >> 4;
  const int cc = tid & 15;
#pragma unroll
  for (int ii = 0; ii < 4; ++ii) {
    const int kr = rr + ii * 16;
    int gr = k0 + kr;
    if (REMAP) gr = ((gr >> 6) << 7) + (gr & 63);
    const float4 v = *(const float4*)&in[(size_t)gr * Nin + n0 + cc * 4];
    T[kr][cc * 4 + 0] = v.x * scale; T[kr][cc * 4 + 1] = v.y * scale;
    T[kr][cc * 4 + 2] = v.z * scale; T[kr][cc * 4 + 3] = v.w * scale;
  }
  __syncthreads();
#pragma unroll
  for (int ii = 0; ii < 4; ++ii) {
    const int n = rr + ii * 16;
    const short4 s4 = make_short4(f2bf(T[cc * 4 + 0][n]), f2bf(T[cc * 4 + 1][n]),
                                  f2bf(T[cc * 4 + 2][n]), f2bf(T[cc * 4 + 3][n]));
    *(short4*)&out[(size_t)(row_off + n0 + n) * out_ld + k0 + cc * 4] = s4;
  }
}

// ---------------------------------------------------------------------------
// bf16 MFMA GEMM, m97 structure: C[M,N] = A[M,K] @ Bt[N,K]^T.
// ---------------------------------------------------------------------------
template <int EPI>
__global__ __launch_bounds__(256) void gemm_mfma(
    const short* __restrict__ A, const short* __restrict__ Bt,
    float* __restrict__ C0, float* __restrict__ C1, float* __restrict__ C2,
    int M, int N, int K) {
  __shared__ short As[128 * 32];
  __shared__ short Bs[128 * 32];
  const int tid = threadIdx.x;
  const int l = tid & 63, w = tid >> 6;
  const int lr = l & 15, lk = l >> 4;
  const int wm = w >> 1, wn = w & 1;
  const int row0 = blockIdx.y * 128, col0 = blockIdx.x * 128;

  f32x4 acc[4][4] = {};

  for (int k0 = 0; k0 < K; k0 += 32) {
    __syncthreads();
#pragma unroll
    for (int j = 0; j < 2; ++j) {
      const int idx = j * 256 + tid;
      const int r = idx >> 2, c = idx & 3;
      gload16(A  + (size_t)(row0 + r) * K + k0 + c * 8, &As[idx * 8]);
      gload16(Bt + (size_t)(col0 + r) * K + k0 + c * 8, &Bs[idx * 8]);
    }
    __syncthreads();
    bf16x8 af[4], bfr[4];
#pragma unroll
    for (int m = 0; m < 4; ++m)
      af[m] = *(const bf16x8*)&As[(wm * 64 + m * 16 + lr) * 32 + lk * 8];
#pragma unroll
    for (int n = 0; n < 4; ++n)
      bfr[n] = *(const bf16x8*)&Bs[(wn * 64 + n * 16 + lr) * 32 + lk * 8];
#pragma unroll
    for (int m = 0; m < 4; ++m)
#pragma unroll
      for (int n = 0; n < 4; ++n)
        acc[m][n] = __builtin_amdgcn_mfma_f32_16x16x32_bf16(af[m], bfr[n],
                                                            acc[m][n], 0, 0, 0);
  }

  float* dst; int ld, cb;
  if (EPI == 0) { dst = C0; ld = N; cb = col0; }
  else if (col0 < 2048)      { dst = C0; ld = 2048; cb = col0; }
  else if (col0 < 2560)      { dst = C1; ld = 512;  cb = col0 - 2048; }
  else                       { dst = C2; ld = 512;  cb = col0 - 2560; }
  const int crow0 = row0 + wm * 64 + lk * 4;
  const int ccol0 = cb + wn * 64 + lr;
#pragma unroll
  for (int m = 0; m < 4; ++m)
#pragma unroll
    for (int n = 0; n < 4; ++n)
#pragma unroll
      for (int rr = 0; rr < 4; ++rr)
        dst[(size_t)(crow0 + m * 16 + rr) * ld + ccol0 + n * 16] = acc[m][n][rr];
}

// ---------------------------------------------------------------------------
// Fused RoPE + latent projection (MFMA).
// in: fp32 [token][nh][128].  WT: bf16 [64 latent][128 d] (pre-scaled).
// ROPE: apply rotate-half RoPE in-register using the per-token cos/sin table.
// TR=false: out[(b*nh+h)][s][64] bf16.   TR=true: out[(b*nh+h)][l][S] bf16.
//
// Block = 256 (4 waves); wave w handles 16 tokens s0+w*16..+15 of one (b,h).
// A-fragments are built in registers straight from global (k-chunks at
// +0/+32/+64/+96: the RoPE partner k+-64 lives in the same thread, chunks
// ch and ch+2). B-fragments read directly from WT (16 KB, L1-resident).
// The lane->k mapping assumption cancels between A and B; RoPE pairing uses
// the true k index, so correctness is mapping-independent.
// ---------------------------------------------------------------------------
template <bool ROPE, bool TR>
__global__ __launch_bounds__(256) void rope_latent(
    const float* __restrict__ in, const short* __restrict__ WT,
    const float* __restrict__ tbl, short* __restrict__ out, int nh) {
  __shared__ short Tw[4][1280];
  const int tid = threadIdx.x;
  const int lane = tid & 63;
  const int w = tid >> 6;
  const int lr = lane & 15;
  const int lk = lane >> 4;
  const int bh = blockIdx.y;
  const int b = bh / nh, h = bh % nh;
  const int s0 = blockIdx.x * 64;
  const int srow = s0 + w * 16 + lr;           // this lane's A-row token
  const int tok = b * kS + srow;

  // load 4 k-chunks of 8 fp32 each
  const float* ip = in + ((size_t)tok * nh + h) * kD + lk * 8;
  float4 a[4][2];
#pragma unroll
  for (int ch = 0; ch < 4; ++ch) {
    a[ch][0] = *(const float4*)(ip + ch * 32);
    a[ch][1] = *(const float4*)(ip + ch * 32 + 4);
  }
  if (ROPE) {
    const float* tb = tbl + (size_t)tok * 128;
    float4 c0[2], c1[2], sn0[2], sn1[2];
    c0[0]  = *(const float4*)(tb + lk * 8);        c0[1]  = *(const float4*)(tb + lk * 8 + 4);
    c1[0]  = *(const float4*)(tb + 32 + lk * 8);   c1[1]  = *(const float4*)(tb + 32 + lk * 8 + 4);
    sn0[0] = *(const float4*)(tb + 64 + lk * 8);   sn0[1] = *(const float4*)(tb + 64 + lk * 8 + 4);
    sn1[0] = *(const float4*)(tb + 96 + lk * 8);   sn1[1] = *(const float4*)(tb + 96 + lk * 8 + 4);
#pragma unroll
    for (int q = 0; q < 2; ++q) {
      const float4 t0 = a[0][q], t1 = a[1][q], t2 = a[2][q], t3 = a[3][q];
      a[0][q].x = t0.x * c0[q].x - t2.x * sn0[q].x;
      a[0][q].y = t0.y * c0[q].y - t2.y * sn0[q].y;
      a[0][q].z = t0.z * c0[q].z - t2.z * sn0[q].z;
      a[0][q].w = t0.w * c0[q].w - t2.w * sn0[q].w;
      a[2][q].x = t2.x * c0[q].x + t0.x * sn0[q].x;
      a[2][q].y = t2.y * c0[q].y + t0.y * sn0[q].y;
      a[2][q].z = t2.z * c0[q].z + t0.z * sn0[q].z;
      a[2][q].w = t2.w * c0[q].w + t0.w * sn0[q].w;
      a[1][q].x = t1.x * c1[q].x - t3.x * sn1[q].x;
      a[1][q].y = t1.y * c1[q].y - t3.y * sn1[q].y;
      a[1][q].z = t1.z * c1[q].z - t3.z * sn1[q].z;
      a[1][q].w = t1.w * c1[q].w - t3.w * sn1[q].w;
      a[3][q].x = t3.x * c1[q].x + t1.x * sn1[q].x;
      a[3][q].y = t3.y * c1[q].y + t1.y * sn1[q].y;
      a[3][q].z = t3.z * c1[q].z + t1.z * sn1[q].z;
      a[3][q].w = t3.w * c1[q].w + t1.w * sn1[q].w;
    }
  }
  bf16x8 af[4];
#pragma unroll
  for (int ch = 0; ch < 4; ++ch) af[ch] = pack8(a[ch][0], a[ch][1]);

  // MFMA: acc[cb] over 4 k-chunks
  f32x4 acc[4] = {};
#pragma unroll
  for (int cb = 0; cb < 4; ++cb) {
#pragma unroll
    for (int ch = 0; ch < 4; ++ch) {
      const bf16x8 bfrag =
          *(const bf16x8*)&WT[(size_t)(cb * 16 + lr) * kD + ch * 32 + lk * 8];
      acc[cb] = __builtin_amdgcn_mfma_f32_16x16x32_bf16(af[ch], bfrag,
                                                        acc[cb], 0, 0, 0);
    }
  }

  // epilogue via wave-private LDS (cross-lane only within wave)
  short* T = Tw[w];
  if (!TR) {
    // assemble [16 tok][72] then write rows of 64 bf16
#pragma unroll
    for (int cb = 0; cb < 4; ++cb)
#pragma unroll
      for (int r = 0; r < 4; ++r)
        T[(lk * 4 + r) * 72 + cb * 16 + lr] = f2bf(acc[cb][r]);
    asm volatile("s_waitcnt lgkmcnt(0)" ::: "memory");
#pragma unroll
    for (int it = 0; it < 2; ++it) {
      const int idx = it * 64 + lane;
      const int row = idx >> 3, c8 = (idx & 7) << 3;
      *(bf16x8*)&out[((size_t)bh * kS + s0 + w * 16 + row) * kL + c8] =
          *(const bf16x8*)&T[row * 72 + c8];
    }
  } else {
    // assemble [64 latent][20] then write 16-wide s-slices per latent row
#pragma unroll
    for (int cb = 0; cb < 4; ++cb)
#pragma unroll
      for (int r = 0; r < 4; ++r)
        T[(cb * 16 + lr) * 20 + lk * 4 + r] = f2bf(acc[cb][r]);
    asm volatile("s_waitcnt lgkmcnt(0)" ::: "memory");
    const size_t orow = ((size_t)bh * kL + lane) * kS + s0 + w * 16;
#pragma unroll
    for (int c = 0; c < 4; ++c)
      *(short4*)&out[orow + c * 4] = *(const short4*)&T[lane * 20 + c * 4];
  }
}

// ---------------------------------------------------------------------------
// MFMA flash attention, causal, bf16 in/out (fp32 accumulate).
// Block = 512 threads (8 waves) = 128 q rows of one (b,h); grid (S/128, B*H).
// ---------------------------------------------------------------------------
__global__ __launch_bounds__(512) void flash_attn_mfma(
    const short* __restrict__ ql, const short* __restrict__ kl,
    const short* __restrict__ vlT, short* __restrict__ attn_out) {
  constexpr int LDK = 72;
  __shared__ short Kt[64 * LDK];
  __shared__ short Vt[64 * LDK];               // row = latent l, col = key
  __shared__ short Pt[128 * LDK];

  const int tid = threadIdx.x;
  const int lane = tid & 63;
  const int w = tid >> 6;
  const int lr = lane & 15;
  const int lk = lane >> 4;
  const int q0 = blockIdx.x * 128;
  const int bh = blockIdx.y;
  const int b = bh >> 4, h = bh & 15;
  const int hk = h >> 2;
  const int wrow = q0 + w * 16;

  const short* qrow = ql + ((size_t)bh * kS + wrow + lr) * kL;
  bf16x8 qf[2];
  qf[0] = *(const bf16x8*)(qrow + lk * 8);
  qf[1] = *(const bf16x8*)(qrow + 32 + lk * 8);

  f32x4 Of[4] = {};
  float m_r[4], l_r[4];
#pragma unroll
  for (int r = 0; r < 4; ++r) { m_r[r] = -3.0e38f; l_r[r] = 0.f; }

  const size_t kbase = (size_t)(b * kHKV + hk) * kS * kL;
  const size_t vbase = (size_t)(b * kHKV + hk) * kL * kS;
  const int ntiles = q0 / 64 + 2;
  const int sr = tid >> 3, sc8 = (tid & 7) << 3;

  for (int t = 0; t < ntiles; ++t) {
    const int j0 = t * 64;
    __syncthreads();
    *(bf16x8*)&Kt[sr * LDK + sc8] =
        *(const bf16x8*)(kl + kbase + (size_t)(j0 + sr) * kL + sc8);
    *(bf16x8*)&Vt[sr * LDK + sc8] =
        *(const bf16x8*)(vlT + vbase + (size_t)sr * kS + j0 + sc8);
    __syncthreads();

    if (j0 > wrow + 15) continue;

    f32x4 Sf[4];
    __builtin_amdgcn_s_setprio(1);
#pragma unroll
    for (int cb = 0; cb < 4; ++cb) {
      f32x4 acc = {};
#pragma unroll
      for (int ch = 0; ch < 2; ++ch) {
        const bf16x8 kf = *(const bf16x8*)&Kt[(cb * 16 + lr) * LDK + ch * 32 + lk * 8];
        acc = __builtin_amdgcn_mfma_f32_16x16x32_bf16(qf[ch], kf, acc, 0, 0, 0);
      }
      Sf[cb] = acc;
    }
    __builtin_amdgcn_s_setprio(0);

    const bool diag = (j0 + 63 > wrow);
    float mt[4] = {-3.0e38f, -3.0e38f, -3.0e38f, -3.0e38f};
#pragma unroll
    for (int cb = 0; cb < 4; ++cb)
#pragma unroll
      for (int r = 0; r < 4; ++r) {
        float s = Sf[cb][r];
        if (diag && (j0 + cb * 16 + lr) > (wrow + lk * 4 + r)) s = -3.0e38f;
        Sf[cb][r] = s;
        mt[r] = fmaxf(mt[r], s);
      }
#pragma unroll
    for (int d = 1; d < 16; d <<= 1)
#pragma unroll
      for (int r = 0; r < 4; ++r) mt[r] = fmaxf(mt[r], __shfl_xor(mt[r], d));

    float corr[4];
#pragma unroll
    for (int r = 0; r < 4; ++r) {
      const float mnew = fmaxf(m_r[r], mt[r]);
      corr[r] = __expf(m_r[r] - mnew);
      m_r[r] = mnew;
      l_r[r] *= corr[r];
    }
#pragma unroll
    for (int cb = 0; cb < 4; ++cb)
#pragma unroll
      for (int r = 0; r < 4; ++r) {
        const float p = __expf(Sf[cb][r] - m_r[r]);
        l_r[r] += p;
        Pt[(w * 16 + lk * 4 + r) * LDK + cb * 16 + lr] = f2bf(p);
      }
    asm volatile("s_waitcnt lgkmcnt(0)" ::: "memory");

    __builtin_amdgcn_s_setprio(1);
#pragma unroll
    for (int cb = 0; cb < 4; ++cb) {
      f32x4 acc = Of[cb];
#pragma unroll
      for (int r = 0; r < 4; ++r) acc[r] *= corr[r];
#pragma unroll
      for (int ch = 0; ch < 2; ++ch) {
        const bf16x8 pf = *(const bf16x8*)&Pt[(w * 16 + lr) * LDK + ch * 32 + lk * 8];
        const bf16x8 vf = *(const bf16x8*)&Vt[(cb * 16 + lr) * LDK + ch * 32 + lk * 8];
        acc = __builtin_amdgcn_mfma_f32_16x16x32_bf16(pf, vf, acc, 0, 0, 0);
      }
      Of[cb] = acc;
    }
    __builtin_amdgcn_s_setprio(0);
  }

#pragma unroll
  for (int d = 1; d < 16; d <<= 1)
#pragma unroll
    for (int r = 0; r < 4; ++r) l_r[r] += __shfl_xor(l_r[r], d);

#pragma unroll
  for (int r = 0; r < 4; ++r) {
    const float inv = 1.f / l_r[r];
    const size_t row = (size_t)(b * kS + wrow + lk * 4 + r) * (kH * kL);
#pragma unroll
    for (int cb = 0; cb < 4; ++cb)
      attn_out[row + h * kL + cb * 16 + lr] = f2bf(Of[cb][r] * inv);
  }
}

// ---------------------------------------------------------------------------
extern "C" void kernel_launch(void* const* d_in, const int* in_sizes, int n_in,
                              void* d_out, int out_size, void* d_ws, size_t ws_size,
                              hipStream_t stream) {
  const float* x    = (const float*)d_in[0];
  const int*   pos  = (const int*)d_in[1];
  const float* Wq   = (const float*)d_in[3];
  const float* Wk   = (const float*)d_in[4];
  const float* Wv   = (const float*)d_in[5];
  const float* Wql  = (const float*)d_in[6];
  const float* Wkl  = (const float*)d_in[7];
  const float* Wvl  = (const float*)d_in[8];
  const float* Wo   = (const float*)d_in[9];
  float* out = (float*)d_out;

  // Workspace carve
  char* p = (char*)d_ws;
  short* x_bf  = (short*)p; p += (size_t)kTok * kHID * 2;        // 16 MB
  short* Wqkv  = (short*)p; p += (size_t)kNQKV * kHID * 2;       // 12.6 MB
  short* WoT   = (short*)p; p += (size_t)kHID * (kH * kL) * 2;   // 4 MB
  short* WqlT  = (short*)p; p += (size_t)kL * kD * 2;            // 16 KB
  short* WklT  = (short*)p; p += (size_t)kL * kD * 2;
  short* WvlT  = (short*)p; p += (size_t)kL * kD * 2;
  float* tbl   = (float*)p; p += (size_t)kTok * 128 * 4;         // 2 MB
  float* k_buf = (float*)p; p += (size_t)kTok * kHKV * kD * 4;   // 8 MB
  float* v_buf = (float*)p; p += (size_t)kTok * kHKV * kD * 4;   // 8 MB
  short* q_l   = (short*)p; p += (size_t)kB * kH * kS * kL * 2;  // 8 MB
  short* k_l   = (short*)p; p += (size_t)kB * kHKV * kS * kL * 2;
  short* v_lT  = (short*)p; p += (size_t)kB * kHKV * kS * kL * 2;
  short* attn  = (short*)p;                                      // 8 MB
  float* q_buf = (float*)d_out;   // scratch until final GEMM

  // 0) dtype prep: x -> bf16; transposed bf16 weights; RoPE trig table
  cvt_bf16<<<kTok * kHID / 8 / 256, 256, 0, stream>>>(x, x_bf, kTok * kHID / 8);
  trig_table<<<kTok * 64 / 256, 256, 0, stream>>>(pos, tbl);
  transpose_cvt<false><<<dim3(kH * kD / 64, kHID / 64), 256, 0, stream>>>(
      Wq, Wqkv, kH * kD, kHID, 0, 1.0f);
  transpose_cvt<false><<<dim3(kHKV * kD / 64, kHID / 64), 256, 0, stream>>>(
      Wk, Wqkv, kHKV * kD, kHID, kH * kD, 1.0f);
  transpose_cvt<false><<<dim3(kHKV * kD / 64, kHID / 64), 256, 0, stream>>>(
      Wv, Wqkv, kHKV * kD, kHID, kH * kD + kHKV * kD, 1.0f);
  transpose_cvt<true><<<dim3(kHID / 64, (kH * kL) / 64), 256, 0, stream>>>(
      Wo, WoT, kHID, kH * kL, 0, 1.0f);
  transpose_cvt<false><<<dim3(1, kD / 64), 256, 0, stream>>>(
      Wql, WqlT, kL, kD, 0, 0.125f);            // fold 1/sqrt(L)
  transpose_cvt<false><<<dim3(1, kD / 64), 256, 0, stream>>>(
      Wkl, WklT, kL, kD, 0, 1.0f);
  transpose_cvt<false><<<dim3(1, kD / 64), 256, 0, stream>>>(
      Wvl, WvlT, kL, kD, 0, 1.0f);

  // 1) Fused QKV projection (MFMA)
  gemm_mfma<1><<<dim3(kNQKV / 128, kTok / 128), 256, 0, stream>>>(
      x_bf, Wqkv, q_buf, k_buf, v_buf, kTok, kNQKV, kHID);

  // 2) Fused RoPE + latent projections (MFMA)
  rope_latent<true,  false><<<dim3(kS / 64, kB * kH), 256, 0, stream>>>(
      q_buf, WqlT, tbl, q_l, kH);
  rope_latent<true,  false><<<dim3(kS / 64, kB * kHKV), 256, 0, stream>>>(
      k_buf, WklT, tbl, k_l, kHKV);
  rope_latent<false, true><<<dim3(kS / 64, kB * kHKV), 256, 0, stream>>>(
      v_buf, WvlT, tbl, v_lT, kHKV);

  // 3) MFMA flash attention (128 q-rows/block, 8 waves)
  flash_attn_mfma<<<dim3(kS / 128, kB * kH), 512, 0, stream>>>(
      q_l, k_l, v_lT, attn);

  // 4) Output GEMM (MFMA): [4096x1024] @ WoT^T -> d_out
  gemm_mfma<0><<<dim3(kHID / 128, kTok / 128), 256, 0, stream>>>(
      attn, WoT, out, nullptr, nullptr, kTok, kHID, kH * kL);
}

// Round 6
// 240.639 us; speedup vs baseline: 12.4603x; 1.0773x over previous
//
#include <hip/hip_runtime.h>
#include <cstddef>

// Problem constants
constexpr int kB   = 2;
constexpr int kS   = 2048;
constexpr int kHID = 2048;
constexpr int kH   = 16;
constexpr int kHKV = 4;
constexpr int kD   = 128;
constexpr int kL   = 64;
constexpr int kTok = kB * kS;             // 4096 tokens
constexpr int kNQKV = kH * kD + 2 * kHKV * kD;  // 3072 fused QKV cols

typedef __attribute__((ext_vector_type(8))) short bf16x8;
typedef __attribute__((ext_vector_type(4))) float f32x4;

static __device__ __forceinline__ short f2bf(float f) {
  union { float f; unsigned u; } v{f};
  const unsigned r = (v.u + 0x7fff + ((v.u >> 16) & 1)) >> 16;
  return (short)r;
}

static __device__ __forceinline__ bf16x8 pack8(float4 a, float4 b) {
  bf16x8 r;
  r[0] = f2bf(a.x); r[1] = f2bf(a.y); r[2] = f2bf(a.z); r[3] = f2bf(a.w);
  r[4] = f2bf(b.x); r[5] = f2bf(b.y); r[6] = f2bf(b.z); r[7] = f2bf(b.w);
  return r;
}

// packed fp32x2 -> bf16x2 (exact RTN) — no builtin on gfx950, inline asm
static __device__ __forceinline__ unsigned cvt_pk_bf16(float lo, float hi) {
  unsigned r;
  asm("v_cvt_pk_bf16_f32 %0, %1, %2" : "=v"(r) : "v"(lo), "v"(hi));
  return r;
}

// async global->LDS, 16B per lane. LDS dest must be wave-uniform base + lane*16.
typedef __attribute__((address_space(3))) void       lds_void;
typedef __attribute__((address_space(1))) const void gm_void;
static __device__ __forceinline__ void gload16(const void* g, void* l) {
  __builtin_amdgcn_global_load_lds((gm_void*)g, (lds_void*)l, 16, 0, 0);
}

// ---------------------------------------------------------------------------
// fp32 -> bf16 elementwise (8 elems / thread)
// ---------------------------------------------------------------------------
__global__ __launch_bounds__(256) void cvt_bf16(const float* __restrict__ in,
                                                short* __restrict__ out, int n8) {
  const int i = blockIdx.x * 256 + threadIdx.x;
  if (i >= n8) return;
  const float4 a = *(const float4*)&in[i * 8];
  const float4 b = *(const float4*)&in[i * 8 + 4];
  *(bf16x8*)&out[i * 8] = pack8(a, b);
}

// ---------------------------------------------------------------------------
// Per-token RoPE cos/sin table
// ---------------------------------------------------------------------------
__global__ __launch_bounds__(256) void trig_table(const int* __restrict__ pos,
                                                  float* __restrict__ tbl) {
  const int idx = blockIdx.x * 256 + threadIdx.x;
  if (idx >= kTok * 64) return;
  const int i = idx & 63, t = idx >> 6;
  const float p = (float)pos[t];
  const float inv_freq = expf(-(float)i * (9.210340371976184f / 64.0f));
  const float ang = p * inv_freq;
  tbl[t * 128 + i]      = cosf(ang);
  tbl[t * 128 + 64 + i] = sinf(ang);
}

// ---------------------------------------------------------------------------
// Transpose + convert + scale: out[row_off+n][k] (bf16, ld) = in[rmap(k)][n]*scale
// ---------------------------------------------------------------------------
template <bool REMAP>
__global__ __launch_bounds__(256) void transpose_cvt(
    const float* __restrict__ in, short* __restrict__ out,
    int Nin, int out_ld, int row_off, float scale) {
  __shared__ float T[64][65];
  const int tid = threadIdx.x;
  const int k0 = blockIdx.y * 64, n0 = blockIdx.x * 64;
  const int rr = tid >> 4;
  const int cc = tid & 15;
#pragma unroll
  for (int ii = 0; ii < 4; ++ii) {
    const int kr = rr + ii * 16;
    int gr = k0 + kr;
    if (REMAP) gr = ((gr >> 6) << 7) + (gr & 63);
    const float4 v = *(const float4*)&in[(size_t)gr * Nin + n0 + cc * 4];
    T[kr][cc * 4 + 0] = v.x * scale; T[kr][cc * 4 + 1] = v.y * scale;
    T[kr][cc * 4 + 2] = v.z * scale; T[kr][cc * 4 + 3] = v.w * scale;
  }
  __syncthreads();
#pragma unroll
  for (int ii = 0; ii < 4; ++ii) {
    const int n = rr + ii * 16;
    const short4 s4 = make_short4(f2bf(T[cc * 4 + 0][n]), f2bf(T[cc * 4 + 1][n]),
                                  f2bf(T[cc * 4 + 2][n]), f2bf(T[cc * 4 + 3][n]));
    *(short4*)&out[(size_t)(row_off + n0 + n) * out_ld + k0 + cc * 4] = s4;
  }
}

// ---------------------------------------------------------------------------
// bf16 MFMA GEMM, m97 structure: C[M,N] = A[M,K] @ Bt[N,K]^T.
// ---------------------------------------------------------------------------
template <int EPI>
__global__ __launch_bounds__(256) void gemm_mfma(
    const short* __restrict__ A, const short* __restrict__ Bt,
    float* __restrict__ C0, float* __restrict__ C1, float* __restrict__ C2,
    int M, int N, int K) {
  __shared__ short As[128 * 32];
  __shared__ short Bs[128 * 32];
  const int tid = threadIdx.x;
  const int l = tid & 63, w = tid >> 6;
  const int lr = l & 15, lk = l >> 4;
  const int wm = w >> 1, wn = w & 1;
  const int row0 = blockIdx.y * 128, col0 = blockIdx.x * 128;

  f32x4 acc[4][4] = {};

  for (int k0 = 0; k0 < K; k0 += 32) {
    __syncthreads();
#pragma unroll
    for (int j = 0; j < 2; ++j) {
      const int idx = j * 256 + tid;
      const int r = idx >> 2, c = idx & 3;
      gload16(A  + (size_t)(row0 + r) * K + k0 + c * 8, &As[idx * 8]);
      gload16(Bt + (size_t)(col0 + r) * K + k0 + c * 8, &Bs[idx * 8]);
    }
    __syncthreads();
    bf16x8 af[4], bfr[4];
#pragma unroll
    for (int m = 0; m < 4; ++m)
      af[m] = *(const bf16x8*)&As[(wm * 64 + m * 16 + lr) * 32 + lk * 8];
#pragma unroll
    for (int n = 0; n < 4; ++n)
      bfr[n] = *(const bf16x8*)&Bs[(wn * 64 + n * 16 + lr) * 32 + lk * 8];
#pragma unroll
    for (int m = 0; m < 4; ++m)
#pragma unroll
      for (int n = 0; n < 4; ++n)
        acc[m][n] = __builtin_amdgcn_mfma_f32_16x16x32_bf16(af[m], bfr[n],
                                                            acc[m][n], 0, 0, 0);
  }

  float* dst; int ld, cb;
  if (EPI == 0) { dst = C0; ld = N; cb = col0; }
  else if (col0 < 2048)      { dst = C0; ld = 2048; cb = col0; }
  else if (col0 < 2560)      { dst = C1; ld = 512;  cb = col0 - 2048; }
  else                       { dst = C2; ld = 512;  cb = col0 - 2560; }
  const int crow0 = row0 + wm * 64 + lk * 4;
  const int ccol0 = cb + wn * 64 + lr;
#pragma unroll
  for (int m = 0; m < 4; ++m)
#pragma unroll
    for (int n = 0; n < 4; ++n)
#pragma unroll
      for (int rr = 0; rr < 4; ++rr)
        dst[(size_t)(crow0 + m * 16 + rr) * ld + ccol0 + n * 16] = acc[m][n][rr];
}

// ---------------------------------------------------------------------------
// Fused RoPE + latent projection (MFMA). See R4 comments.
// ---------------------------------------------------------------------------
template <bool ROPE, bool TR>
__global__ __launch_bounds__(256) void rope_latent(
    const float* __restrict__ in, const short* __restrict__ WT,
    const float* __restrict__ tbl, short* __restrict__ out, int nh) {
  __shared__ short Tw[4][1280];
  const int tid = threadIdx.x;
  const int lane = tid & 63;
  const int w = tid >> 6;
  const int lr = lane & 15;
  const int lk = lane >> 4;
  const int bh = blockIdx.y;
  const int b = bh / nh, h = bh % nh;
  const int s0 = blockIdx.x * 64;
  const int srow = s0 + w * 16 + lr;
  const int tok = b * kS + srow;

  const float* ip = in + ((size_t)tok * nh + h) * kD + lk * 8;
  float4 a[4][2];
#pragma unroll
  for (int ch = 0; ch < 4; ++ch) {
    a[ch][0] = *(const float4*)(ip + ch * 32);
    a[ch][1] = *(const float4*)(ip + ch * 32 + 4);
  }
  if (ROPE) {
    const float* tb = tbl + (size_t)tok * 128;
    float4 c0[2], c1[2], sn0[2], sn1[2];
    c0[0]  = *(const float4*)(tb + lk * 8);        c0[1]  = *(const float4*)(tb + lk * 8 + 4);
    c1[0]  = *(const float4*)(tb + 32 + lk * 8);   c1[1]  = *(const float4*)(tb + 32 + lk * 8 + 4);
    sn0[0] = *(const float4*)(tb + 64 + lk * 8);   sn0[1] = *(const float4*)(tb + 64 + lk * 8 + 4);
    sn1[0] = *(const float4*)(tb + 96 + lk * 8);   sn1[1] = *(const float4*)(tb + 96 + lk * 8 + 4);
#pragma unroll
    for (int q = 0; q < 2; ++q) {
      const float4 t0 = a[0][q], t1 = a[1][q], t2 = a[2][q], t3 = a[3][q];
      a[0][q].x = t0.x * c0[q].x - t2.x * sn0[q].x;
      a[0][q].y = t0.y * c0[q].y - t2.y * sn0[q].y;
      a[0][q].z = t0.z * c0[q].z - t2.z * sn0[q].z;
      a[0][q].w = t0.w * c0[q].w - t2.w * sn0[q].w;
      a[2][q].x = t2.x * c0[q].x + t0.x * sn0[q].x;
      a[2][q].y = t2.y * c0[q].y + t0.y * sn0[q].y;
      a[2][q].z = t2.z * c0[q].z + t0.z * sn0[q].z;
      a[2][q].w = t2.w * c0[q].w + t0.w * sn0[q].w;
      a[1][q].x = t1.x * c1[q].x - t3.x * sn1[q].x;
      a[1][q].y = t1.y * c1[q].y - t3.y * sn1[q].y;
      a[1][q].z = t1.z * c1[q].z - t3.z * sn1[q].z;
      a[1][q].w = t1.w * c1[q].w - t3.w * sn1[q].w;
      a[3][q].x = t3.x * c1[q].x + t1.x * sn1[q].x;
      a[3][q].y = t3.y * c1[q].y + t1.y * sn1[q].y;
      a[3][q].z = t3.z * c1[q].z + t1.z * sn1[q].z;
      a[3][q].w = t3.w * c1[q].w + t1.w * sn1[q].w;
    }
  }
  bf16x8 af[4];
#pragma unroll
  for (int ch = 0; ch < 4; ++ch) af[ch] = pack8(a[ch][0], a[ch][1]);

  f32x4 acc[4] = {};
#pragma unroll
  for (int cb = 0; cb < 4; ++cb) {
#pragma unroll
    for (int ch = 0; ch < 4; ++ch) {
      const bf16x8 bfrag =
          *(const bf16x8*)&WT[(size_t)(cb * 16 + lr) * kD + ch * 32 + lk * 8];
      acc[cb] = __builtin_amdgcn_mfma_f32_16x16x32_bf16(af[ch], bfrag,
                                                        acc[cb], 0, 0, 0);
    }
  }

  short* T = Tw[w];
  if (!TR) {
#pragma unroll
    for (int cb = 0; cb < 4; ++cb)
#pragma unroll
      for (int r = 0; r < 4; ++r)
        T[(lk * 4 + r) * 72 + cb * 16 + lr] = f2bf(acc[cb][r]);
    asm volatile("s_waitcnt lgkmcnt(0)" ::: "memory");
#pragma unroll
    for (int it = 0; it < 2; ++it) {
      const int idx = it * 64 + lane;
      const int row = idx >> 3, c8 = (idx & 7) << 3;
      *(bf16x8*)&out[((size_t)bh * kS + s0 + w * 16 + row) * kL + c8] =
          *(const bf16x8*)&T[row * 72 + c8];
    }
  } else {
#pragma unroll
    for (int cb = 0; cb < 4; ++cb)
#pragma unroll
      for (int r = 0; r < 4; ++r)
        T[(cb * 16 + lr) * 20 + lk * 4 + r] = f2bf(acc[cb][r]);
    asm volatile("s_waitcnt lgkmcnt(0)" ::: "memory");
    const size_t orow = ((size_t)bh * kL + lane) * kS + s0 + w * 16;
#pragma unroll
    for (int c = 0; c < 4; ++c)
      *(short4*)&out[orow + c * 4] = *(const short4*)&T[lane * 20 + c * 4];
  }
}

// ---------------------------------------------------------------------------
// MFMA flash attention, causal, bf16 in/out (fp32 accumulate).
// Block = 512 threads (8 waves) = 128 q rows of one (b,h).
// grid = (B*H, S/128) with bx remap pairing heavy+light blocks per CU:
// bid<8 -> bx=2*bid, else bx=31-2*bid; CU gets (2b, 15-2b): constant work.
// T13 defer-max (THR=8) skips the O-rescale when max growth is small.
// ---------------------------------------------------------------------------
__global__ __launch_bounds__(512) void flash_attn_mfma(
    const short* __restrict__ ql, const short* __restrict__ kl,
    const short* __restrict__ vlT, short* __restrict__ attn_out) {
  constexpr int LDK = 72;
  __shared__ short Kt[64 * LDK];
  __shared__ short Vt[64 * LDK];               // row = latent l, col = key
  __shared__ short Pt[128 * LDK];

  const int tid = threadIdx.x;
  const int lane = tid & 63;
  const int w = tid >> 6;
  const int lr = lane & 15;
  const int lk = lane >> 4;
  const int bid = blockIdx.y;
  const int bx = (bid < 8) ? (2 * bid) : (31 - 2 * bid);   // load-balance remap
  const int q0 = bx * 128;
  const int bh = blockIdx.x;
  const int b = bh >> 4, h = bh & 15;
  const int hk = h >> 2;
  const int wrow = q0 + w * 16;

  const short* qrow = ql + ((size_t)bh * kS + wrow + lr) * kL;
  bf16x8 qf[2];
  qf[0] = *(const bf16x8*)(qrow + lk * 8);
  qf[1] = *(const bf16x8*)(qrow + 32 + lk * 8);

  f32x4 Of[4] = {};
  float m_r[4], l_r[4];
#pragma unroll
  for (int r = 0; r < 4; ++r) { m_r[r] = -3.0e38f; l_r[r] = 0.f; }

  const size_t kbase = (size_t)(b * kHKV + hk) * kS * kL;
  const size_t vbase = (size_t)(b * kHKV + hk) * kL * kS;
  const int ntiles = q0 / 64 + 2;
  const int sr = tid >> 3, sc8 = (tid & 7) << 3;

  for (int t = 0; t < ntiles; ++t) {
    const int j0 = t * 64;
    __syncthreads();
    *(bf16x8*)&Kt[sr * LDK + sc8] =
        *(const bf16x8*)(kl + kbase + (size_t)(j0 + sr) * kL + sc8);
    *(bf16x8*)&Vt[sr * LDK + sc8] =
        *(const bf16x8*)(vlT + vbase + (size_t)sr * kS + j0 + sc8);
    __syncthreads();

    if (j0 > wrow + 15) continue;

    f32x4 Sf[4];
    __builtin_amdgcn_s_setprio(1);
#pragma unroll
    for (int cb = 0; cb < 4; ++cb) {
      f32x4 acc = {};
#pragma unroll
      for (int ch = 0; ch < 2; ++ch) {
        const bf16x8 kf = *(const bf16x8*)&Kt[(cb * 16 + lr) * LDK + ch * 32 + lk * 8];
        acc = __builtin_amdgcn_mfma_f32_16x16x32_bf16(qf[ch], kf, acc, 0, 0, 0);
      }
      Sf[cb] = acc;
    }
    __builtin_amdgcn_s_setprio(0);

    const bool diag = (j0 + 63 > wrow);
    float mt[4] = {-3.0e38f, -3.0e38f, -3.0e38f, -3.0e38f};
#pragma unroll
    for (int cb = 0; cb < 4; ++cb)
#pragma unroll
      for (int r = 0; r < 4; ++r) {
        float s = Sf[cb][r];
        if (diag && (j0 + cb * 16 + lr) > (wrow + lk * 4 + r)) s = -3.0e38f;
        Sf[cb][r] = s;
        mt[r] = fmaxf(mt[r], s);
      }
#pragma unroll
    for (int d = 1; d < 16; d <<= 1)
#pragma unroll
      for (int r = 0; r < 4; ++r) mt[r] = fmaxf(mt[r], __shfl_xor(mt[r], d));

    // T13 defer-max: only rescale when some row's max grew by > 8
    const bool need = (mt[0] > m_r[0] + 8.f) || (mt[1] > m_r[1] + 8.f) ||
                      (mt[2] > m_r[2] + 8.f) || (mt[3] > m_r[3] + 8.f);
    const bool resc = __any((int)need);        // wave-uniform
    float corr[4] = {1.f, 1.f, 1.f, 1.f};
    if (resc) {
#pragma unroll
      for (int r = 0; r < 4; ++r) {
        const float mnew = fmaxf(m_r[r], mt[r]);
        corr[r] = __expf(m_r[r] - mnew);
        m_r[r] = mnew;
        l_r[r] *= corr[r];
      }
    }
#pragma unroll
    for (int cb = 0; cb < 4; ++cb) {
      const float p0 = __expf(Sf[cb][0] - m_r[0]);
      const float p1 = __expf(Sf[cb][1] - m_r[1]);
      const float p2 = __expf(Sf[cb][2] - m_r[2]);
      const float p3 = __expf(Sf[cb][3] - m_r[3]);
      l_r[0] += p0; l_r[1] += p1; l_r[2] += p2; l_r[3] += p3;
      const unsigned pk01 = cvt_pk_bf16(p0, p1);
      const unsigned pk23 = cvt_pk_bf16(p2, p3);
      short* prow = &Pt[(w * 16 + lk * 4) * LDK + cb * 16 + lr];
      prow[0 * LDK] = (short)(pk01 & 0xffff);
      prow[1 * LDK] = (short)(pk01 >> 16);
      prow[2 * LDK] = (short)(pk23 & 0xffff);
      prow[3 * LDK] = (short)(pk23 >> 16);
    }
    asm volatile("s_waitcnt lgkmcnt(0)" ::: "memory");

    __builtin_amdgcn_s_setprio(1);
#pragma unroll
    for (int cb = 0; cb < 4; ++cb) {
      f32x4 acc = Of[cb];
      if (resc) {
#pragma unroll
        for (int r = 0; r < 4; ++r) acc[r] *= corr[r];
      }
#pragma unroll
      for (int ch = 0; ch < 2; ++ch) {
        const bf16x8 pf = *(const bf16x8*)&Pt[(w * 16 + lr) * LDK + ch * 32 + lk * 8];
        const bf16x8 vf = *(const bf16x8*)&Vt[(cb * 16 + lr) * LDK + ch * 32 + lk * 8];
        acc = __builtin_amdgcn_mfma_f32_16x16x32_bf16(pf, vf, acc, 0, 0, 0);
      }
      Of[cb] = acc;
    }
    __builtin_amdgcn_s_setprio(0);
  }

#pragma unroll
  for (int d = 1; d < 16; d <<= 1)
#pragma unroll
    for (int r = 0; r < 4; ++r) l_r[r] += __shfl_xor(l_r[r], d);

#pragma unroll
  for (int r = 0; r < 4; ++r) {
    const float inv = 1.f / l_r[r];
    const size_t row = (size_t)(b * kS + wrow + lk * 4 + r) * (kH * kL);
#pragma unroll
    for (int cb = 0; cb < 4; ++cb)
      attn_out[row + h * kL + cb * 16 + lr] = f2bf(Of[cb][r] * inv);
  }
}

// ---------------------------------------------------------------------------
extern "C" void kernel_launch(void* const* d_in, const int* in_sizes, int n_in,
                              void* d_out, int out_size, void* d_ws, size_t ws_size,
                              hipStream_t stream) {
  const float* x    = (const float*)d_in[0];
  const int*   pos  = (const int*)d_in[1];
  const float* Wq   = (const float*)d_in[3];
  const float* Wk   = (const float*)d_in[4];
  const float* Wv   = (const float*)d_in[5];
  const float* Wql  = (const float*)d_in[6];
  const float* Wkl  = (const float*)d_in[7];
  const float* Wvl  = (const float*)d_in[8];
  const float* Wo   = (const float*)d_in[9];
  float* out = (float*)d_out;

  // Workspace carve
  char* p = (char*)d_ws;
  short* x_bf  = (short*)p; p += (size_t)kTok * kHID * 2;        // 16 MB
  short* Wqkv  = (short*)p; p += (size_t)kNQKV * kHID * 2;       // 12.6 MB
  short* WoT   = (short*)p; p += (size_t)kHID * (kH * kL) * 2;   // 4 MB
  short* WqlT  = (short*)p; p += (size_t)kL * kD * 2;            // 16 KB
  short* WklT  = (short*)p; p += (size_t)kL * kD * 2;
  short* WvlT  = (short*)p; p += (size_t)kL * kD * 2;
  float* tbl   = (float*)p; p += (size_t)kTok * 128 * 4;         // 2 MB
  float* k_buf = (float*)p; p += (size_t)kTok * kHKV * kD * 4;   // 8 MB
  float* v_buf = (float*)p; p += (size_t)kTok * kHKV * kD * 4;   // 8 MB
  short* q_l   = (short*)p; p += (size_t)kB * kH * kS * kL * 2;  // 8 MB
  short* k_l   = (short*)p; p += (size_t)kB * kHKV * kS * kL * 2;
  short* v_lT  = (short*)p; p += (size_t)kB * kHKV * kS * kL * 2;
  short* attn  = (short*)p;                                      // 8 MB
  float* q_buf = (float*)d_out;   // scratch until final GEMM

  // 0) dtype prep
  cvt_bf16<<<kTok * kHID / 8 / 256, 256, 0, stream>>>(x, x_bf, kTok * kHID / 8);
  trig_table<<<kTok * 64 / 256, 256, 0, stream>>>(pos, tbl);
  transpose_cvt<false><<<dim3(kH * kD / 64, kHID / 64), 256, 0, stream>>>(
      Wq, Wqkv, kH * kD, kHID, 0, 1.0f);
  transpose_cvt<false><<<dim3(kHKV * kD / 64, kHID / 64), 256, 0, stream>>>(
      Wk, Wqkv, kHKV * kD, kHID, kH * kD, 1.0f);
  transpose_cvt<false><<<dim3(kHKV * kD / 64, kHID / 64), 256, 0, stream>>>(
      Wv, Wqkv, kHKV * kD, kHID, kH * kD + kHKV * kD, 1.0f);
  transpose_cvt<true><<<dim3(kHID / 64, (kH * kL) / 64), 256, 0, stream>>>(
      Wo, WoT, kHID, kH * kL, 0, 1.0f);
  transpose_cvt<false><<<dim3(1, kD / 64), 256, 0, stream>>>(
      Wql, WqlT, kL, kD, 0, 0.125f);            // fold 1/sqrt(L)
  transpose_cvt<false><<<dim3(1, kD / 64), 256, 0, stream>>>(
      Wkl, WklT, kL, kD, 0, 1.0f);
  transpose_cvt<false><<<dim3(1, kD / 64), 256, 0, stream>>>(
      Wvl, WvlT, kL, kD, 0, 1.0f);

  // 1) Fused QKV projection (MFMA)
  gemm_mfma<1><<<dim3(kNQKV / 128, kTok / 128), 256, 0, stream>>>(
      x_bf, Wqkv, q_buf, k_buf, v_buf, kTok, kNQKV, kHID);

  // 2) Fused RoPE + latent projections (MFMA)
  rope_latent<true,  false><<<dim3(kS / 64, kB * kH), 256, 0, stream>>>(
      q_buf, WqlT, tbl, q_l, kH);
  rope_latent<true,  false><<<dim3(kS / 64, kB * kHKV), 256, 0, stream>>>(
      k_buf, WklT, tbl, k_l, kHKV);
  rope_latent<false, true><<<dim3(kS / 64, kB * kHKV), 256, 0, stream>>>(
      v_buf, WvlT, tbl, v_lT, kHKV);

  // 3) MFMA flash attention (128 q-rows/block, 8 waves, balanced grid)
  flash_attn_mfma<<<dim3(kB * kH, kS / 128), 512, 0, stream>>>(
      q_l, k_l, v_lT, attn);

  // 4) Output GEMM (MFMA): [4096x1024] @ WoT^T -> d_out
  gemm_mfma<0><<<dim3(kHID / 128, kTok / 128), 256, 0, stream>>>(
      attn, WoT, out, nullptr, nullptr, kTok, kHID, kH * kL);
}